// Round 2
// baseline (866.507 us; speedup 1.0000x reference)
//
#include <hip/hip_runtime.h>

// ---------------------------------------------------------------------------
// MRLR feature extractor: per-item 2-mode ALS (PARAFAC) done in the small
// 96-dim space.  out = (W1 + W2 - W2*W1) @ X  per item.
// Stages:
//   memset: zero M/C/G accumulators (ws poisoned once; atomics need zeros)
//   k1: split-K, atomicAdd into M = X X^T, C = X [B01|B02], G0 = B0^T B0
//   k3: per-item ALS chain entirely in LDS (one WG per item)
//   k4: out = T @ X
// ---------------------------------------------------------------------------

#define TID ((int)threadIdx.x)
typedef float4 f4;

#define NCH 24
#define CHK 384   // 9216 / NCH

// workspace layout (float offsets) — total 333,056 floats = 1.33 MB
#define OFF_MG    0        // 8 * 9216
#define OFF_C48   73728    // 8 * 4608
#define OFF_G0    110592   // 1280
#define OFF_TMPG  111872   // 8 * 9216
#define OFF_TMPT  185600   // 8 * 9216
#define OFF_TG    259328   // 8 * 9216
#define ACC_FLOATS 111872  // zeroed each launch (MG + C48 + G0)

__device__ __forceinline__ f4 ld4(const float* p) { return *(const f4*)p; }
__device__ __forceinline__ void st4(float* p, f4 v) { *(f4*)p = v; }
__device__ __forceinline__ f4 f4zero() { return make_float4(0.f, 0.f, 0.f, 0.f); }
__device__ __forceinline__ void fma4(f4& a, float s, f4 v) {
  a.x = fmaf(s, v.x, a.x); a.y = fmaf(s, v.y, a.y);
  a.z = fmaf(s, v.z, a.z); a.w = fmaf(s, v.w, a.w);
}
__device__ __forceinline__ void outer4(f4* acc, f4 u, f4 v) {
  fma4(acc[0], u.x, v); fma4(acc[1], u.y, v);
  fma4(acc[2], u.z, v); fma4(acc[3], u.w, v);
}
__device__ __forceinline__ float getc(f4 v, int u) {
  return u == 0 ? v.x : (u == 1 ? v.y : (u == 2 ? v.z : v.w));
}

// ---------------------------------------------------------------------------
// k1: split-K partial outer products, accumulated via f32 atomics.
// grid (NCH, 8), block 256.
// tasks: 144 M-tiles (8x8 over 96x96), 72 C-tiles (8x8 over 96x48),
//        16 G01-tiles, 4 G02-tiles (item 0 only).
// ---------------------------------------------------------------------------
__global__ __launch_bounds__(256) void k1_partials(
    const float* __restrict__ x, const float* __restrict__ b01,
    const float* __restrict__ b02, float* __restrict__ ws) {
  __shared__ __align__(16) float Xst[64][100];  // transposed X slab (k-major)
  __shared__ __align__(16) float Bs[64][52];    // [B01 | B02] slab (k-major)
  int kc = blockIdx.x, item = blockIdx.y;
  const float* X = x + (size_t)item * 96 * 9216;

  const float* ap = nullptr; const float* bp = nullptr;
  int asr = 0, bsr = 0, os = 0;
  float* op = nullptr;
  bool active = false;
  {
    int t = TID;
    if (t < 144) {
      int i0 = (t / 12) * 8, j0 = (t % 12) * 8;
      ap = &Xst[0][i0]; asr = 100; bp = &Xst[0][j0]; bsr = 100;
      op = ws + OFF_MG + (size_t)item * 9216 + i0 * 96 + j0;
      os = 96; active = true;
    } else if (t < 216) {
      int u = t - 144; int i0 = (u / 6) * 8, c0 = (u % 6) * 8;
      ap = &Xst[0][i0]; asr = 100; bp = &Bs[0][c0]; bsr = 52;
      op = ws + OFF_C48 + (size_t)item * 4608 + i0 * 48 + c0;
      os = 48; active = true;
    } else if (t < 232) {
      int u = t - 216; int a0 = (u / 4) * 8, b0 = (u % 4) * 8;
      ap = &Bs[0][a0]; asr = 52; bp = &Bs[0][b0]; bsr = 52;
      op = ws + OFF_G0 + a0 * 32 + b0;
      os = 32; active = (item == 0);
    } else if (t < 236) {
      int u = t - 232; int a0 = (u / 2) * 8, b0 = (u % 2) * 8;
      ap = &Bs[0][32 + a0]; asr = 52; bp = &Bs[0][32 + b0]; bsr = 52;
      op = ws + OFF_G0 + 1024 + a0 * 16 + b0;
      os = 16; active = (item == 0);
    }
  }

  f4 acc[8][2];
  #pragma unroll
  for (int a = 0; a < 8; ++a) { acc[a][0] = f4zero(); acc[a][1] = f4zero(); }

  for (int sc = 0; sc < 6; ++sc) {
    int k0 = kc * CHK + sc * 64;
    __syncthreads();  // previous sub-chunk compute done before overwrite
    for (int e = TID; e < 1536; e += 256) {          // X slab, transposed store
      int i = e / 16, kq = (e % 16) * 4;
      f4 v = ld4(&X[(size_t)i * 9216 + k0 + kq]);
      Xst[kq][i] = v.x; Xst[kq + 1][i] = v.y; Xst[kq + 2][i] = v.z; Xst[kq + 3][i] = v.w;
    }
    for (int e = TID; e < 512; e += 256) {           // B01 slab
      int kk = e / 8, cq = (e % 8) * 4;
      st4(&Bs[kk][cq], ld4(&b01[(size_t)(k0 + kk) * 32 + cq]));
    }
    for (int e = TID; e < 256; e += 256) {           // B02 slab
      int kk = e / 4, cq = (e % 4) * 4;
      st4(&Bs[kk][32 + cq], ld4(&b02[(size_t)(k0 + kk) * 16 + cq]));
    }
    __syncthreads();
    if (active) {
      for (int kk = 0; kk < 64; ++kk) {
        const float* ar = ap + kk * asr;
        const float* br = bp + kk * bsr;
        f4 b0v = ld4(br), b1v = ld4(br + 4);
        f4 a0v = ld4(ar), a1v = ld4(ar + 4);
        float aa[8] = {a0v.x, a0v.y, a0v.z, a0v.w, a1v.x, a1v.y, a1v.z, a1v.w};
        #pragma unroll
        for (int a = 0; a < 8; ++a) { fma4(acc[a][0], aa[a], b0v); fma4(acc[a][1], aa[a], b1v); }
      }
    }
  }
  if (active) {
    #pragma unroll
    for (int a = 0; a < 8; ++a) {
      float vals[8] = {acc[a][0].x, acc[a][0].y, acc[a][0].z, acc[a][0].w,
                       acc[a][1].x, acc[a][1].y, acc[a][1].z, acc[a][1].w};
      #pragma unroll
      for (int u = 0; u < 8; ++u) atomicAdd(op + a * os + u, vals[u]);
    }
  }
}

// ---------------------------------------------------------------------------
// k3 helpers
// ---------------------------------------------------------------------------

// Unnormalized Gauss-Jordan on aug[r][0:C]; solves L Z = RHS where
// L = aug[:, 0:r], RHS = aug[:, r:C]; result Z left in aug[:, r:C].
// Pivot column for each step is cached in double-buffered colbuf to avoid
// the read/write race; eliminated columns are explicitly zeroed so the
// diagonal stays exact.  One barrier per elimination step.
__device__ void gauss_jordan(float (*aug)[64], float (*colbuf)[32], int r, int C) {
  int noct = C >> 3;
  int nthr = r * noct;
  __syncthreads();                      // aug writes visible, colbuf free
  if (TID < r) colbuf[0][TID] = aug[TID][0];
  for (int c = 0; c < r; ++c) {
    __syncthreads();
    if (TID < nthr) {
      int i = TID / noct, j0 = (TID % noct) * 8;
      const float* cb = colbuf[c & 1];
      float f = cb[i] / cb[c];
      int nc = c + 1;
      bool own = (nc < r) && (nc >= j0) && (nc < j0 + 8);
      if (i != c) {
        f4 p0 = ld4(&aug[c][j0]), p1 = ld4(&aug[c][j0 + 4]);
        f4 v0 = ld4(&aug[i][j0]), v1 = ld4(&aug[i][j0 + 4]);
        float pr[8] = {p0.x, p0.y, p0.z, p0.w, p1.x, p1.y, p1.z, p1.w};
        float vv[8] = {v0.x, v0.y, v0.z, v0.w, v1.x, v1.y, v1.z, v1.w};
        #pragma unroll
        for (int u = 0; u < 8; ++u)
          vv[u] = (j0 + u == c) ? 0.f : fmaf(-f, pr[u], vv[u]);
        st4(&aug[i][j0], make_float4(vv[0], vv[1], vv[2], vv[3]));
        st4(&aug[i][j0 + 4], make_float4(vv[4], vv[5], vv[6], vv[7]));
        if (own) colbuf[nc & 1][i] = vv[nc - j0];
      } else {
        if (own) colbuf[nc & 1][i] = aug[c][nc];   // pivot row unchanged
      }
    }
  }
  __syncthreads();
  int w = C - r;
  int nq = r * (w >> 2);
  if (TID < nq) {
    int i = TID / (w >> 2), jq = (TID % (w >> 2)) * 4;
    float d = aug[i][i];
    f4 z = ld4(&aug[i][r + jq]);
    z.x /= d; z.y /= d; z.z /= d; z.w /= d;
    st4(&aug[i][r + jq], z);
  }
  __syncthreads();
}

__device__ __forceinline__ void store_dual(float (*Os)[32], float (*Ot)[100],
                                           int i0, int c0, const f4* acc) {
  #pragma unroll
  for (int a = 0; a < 4; ++a) st4(&Os[i0 + a][c0], acc[a]);
  #pragma unroll
  for (int b = 0; b < 4; ++b)
    st4(&Ot[c0 + b][i0],
        make_float4(getc(acc[0], b), getc(acc[1], b), getc(acc[2], b), getc(acc[3], b)));
}

// OUT[i][c] = sum_k Lt[k*ls + i] * R[k*rs + c]; dual-stored (normal+transposed)
__device__ __forceinline__ void mm_dual(const float* Lt, int ls, const float* R, int rs,
                                        int kn, int ntc, float (*Os)[32], float (*Ot)[100]) {
  if (TID < 24 * ntc) {
    int i0 = (TID / ntc) * 4, c0 = (TID % ntc) * 4;
    f4 acc[4]; acc[0] = acc[1] = acc[2] = acc[3] = f4zero();
    #pragma unroll 4
    for (int k = 0; k < kn; ++k)
      outer4(acc, ld4(Lt + (size_t)k * ls + i0), ld4(R + (size_t)k * rs + c0));
    store_dual(Os, Ot, i0, c0, acc);
  }
}

// S = MA^T A -> aug[:,0:r], G = A^T A -> aug[:,r:2r]
__device__ __forceinline__ void phase_SG(const float (*MAs)[32], const float (*As)[32],
                                         float (*aug)[64], int r) {
  int nt4 = r >> 2, nt = nt4 * nt4;
  if (TID < 2 * nt) {
    int which = (TID >= nt);
    int t = which ? TID - nt : TID;
    int a0 = (t / nt4) * 4, b0 = (t % nt4) * 4;
    const float* L = which ? &As[0][0] : &MAs[0][0];
    f4 acc[4]; acc[0] = acc[1] = acc[2] = acc[3] = f4zero();
    #pragma unroll 4
    for (int k = 0; k < 96; ++k)
      outer4(acc, ld4(&L[k * 32 + a0]), ld4(&As[k][b0]));
    int cbase = which ? r + b0 : b0;
    #pragma unroll
    for (int a = 0; a < 4; ++a) st4(&aug[a0 + a][cbase], acc[a]);
  }
}

// G = A^T A -> aug[:,0:r];  I -> aug[:,r:2r]
__device__ __forceinline__ void phase_Gid(const float (*As)[32], float (*aug)[64], int r) {
  int nt4 = r >> 2, nt = nt4 * nt4;
  if (TID < nt) {
    int a0 = (TID / nt4) * 4, b0 = (TID % nt4) * 4;
    f4 acc[4]; acc[0] = acc[1] = acc[2] = acc[3] = f4zero();
    #pragma unroll 4
    for (int k = 0; k < 96; ++k)
      outer4(acc, ld4(&As[k][a0]), ld4(&As[k][b0]));
    #pragma unroll
    for (int a = 0; a < 4; ++a) st4(&aug[a0 + a][b0], acc[a]);
  } else if (TID < nt + r) {
    int i = TID - nt;
    for (int j = 0; j < r; j += 4)
      st4(&aug[i][r + j], make_float4(i == j ? 1.f : 0.f, i == j + 1 ? 1.f : 0.f,
                                      i == j + 2 ? 1.f : 0.f, i == j + 3 ? 1.f : 0.f));
  }
}

// W = AK @ A^T  (96x96) using transposed operands
__device__ __forceinline__ void phase_W(const float (*AKt)[100], const float (*At)[100],
                                        int r, float (*W)[96]) {
  for (int t = TID; t < 576; t += 256) {
    int i0 = (t / 24) * 4, j0 = (t % 24) * 4;
    f4 acc[4]; acc[0] = acc[1] = acc[2] = acc[3] = f4zero();
    #pragma unroll 4
    for (int c = 0; c < r; ++c)
      outer4(acc, ld4(&AKt[c][i0]), ld4(&At[c][j0]));
    #pragma unroll
    for (int a = 0; a < 4; ++a) st4(&W[i0 + a][j0], acc[a]);
  }
}

// ---------------------------------------------------------------------------
// k3: per-item ALS chain.  grid (8), block 256.
// ---------------------------------------------------------------------------
__global__ __launch_bounds__(256) void k3_als(float* __restrict__ ws) {
  __shared__ __align__(16) float Ms[96][96];
  __shared__ __align__(16) float As[96][32];
  __shared__ __align__(16) float Ast[32][100];
  __shared__ __align__(16) float MAs[96][32];
  __shared__ __align__(16) float MAt[32][100];
  __shared__ __align__(16) float Ws[96][96];
  __shared__ __align__(16) float aug[32][64];
  __shared__ __align__(16) float colbuf[2][32];

  int item = blockIdx.x;
  const float* Mg  = ws + OFF_MG  + (size_t)item * 9216;
  const float* C48 = ws + OFF_C48 + (size_t)item * 4608;
  const float* G0  = ws + OFF_G0;
  float* TMPg = ws + OFF_TMPG + (size_t)item * 9216;
  float* TMPt = ws + OFF_TMPT + (size_t)item * 9216;
  float* Tg   = ws + OFF_TG   + (size_t)item * 9216;

  // ph0: load M into LDS
  for (int e = TID * 4; e < 9216; e += 1024) {
    f4 v = ld4(&Mg[e]);
    st4(&Ms[e / 96][e % 96], v);
  }
  // ph1: aug = [G01 | I]
  {
    int e = TID * 8; int i = e / 64, j = e % 64;
    #pragma unroll
    for (int u = 0; u < 8; ++u) {
      int jj = j + u;
      aug[i][jj] = (jj < 32) ? G0[i * 32 + jj] : ((jj - 32 == i) ? 1.f : 0.f);
    }
  }
  gauss_jordan(aug, colbuf, 32, 64);  // aug[:,32:64] = K0 = inv(G01)

  // ph2: A1 = C1 @ K0 (k-quad over 32)
  if (TID < 192) {
    int i0 = (TID / 8) * 4, c0 = (TID % 8) * 4;
    f4 acc[4]; acc[0] = acc[1] = acc[2] = acc[3] = f4zero();
    for (int kq = 0; kq < 8; ++kq) {
      f4 zrow[4], crow[4];
      #pragma unroll
      for (int u = 0; u < 4; ++u) zrow[u] = ld4(&aug[kq * 4 + u][32 + c0]);
      #pragma unroll
      for (int a = 0; a < 4; ++a) crow[a] = ld4(&C48[(i0 + a) * 48 + kq * 4]);
      #pragma unroll
      for (int a = 0; a < 4; ++a) {
        fma4(acc[a], crow[a].x, zrow[0]); fma4(acc[a], crow[a].y, zrow[1]);
        fma4(acc[a], crow[a].z, zrow[2]); fma4(acc[a], crow[a].w, zrow[3]);
      }
    }
    store_dual(As, Ast, i0, c0, acc);
  }
  __syncthreads();

  // partition 1: 14 recursions, r = 32
  for (int it = 0; it < 14; ++it) {
    mm_dual(&Ms[0][0], 96, &As[0][0], 32, 96, 8, MAs, MAt);   // MA = M @ A
    __syncthreads();
    phase_SG(MAs, As, aug, 32);                               // [S | G]
    __syncthreads();
    gauss_jordan(aug, colbuf, 32, 64);                        // Z = S^-1 G
    mm_dual(&MAt[0][0], 100, &aug[0][32], 64, 32, 8, As, Ast); // A = MA @ Z
    __syncthreads();
  }

  // W1 = A inv(A^T A) A^T
  phase_Gid(As, aug, 32);
  gauss_jordan(aug, colbuf, 32, 64);                          // K = inv(G)
  mm_dual(&Ast[0][0], 100, &aug[0][32], 64, 32, 8, MAs, MAt); // AK = A @ K
  __syncthreads();
  phase_W(MAt, Ast, 32, Ws);                                  // W1 -> Ws
  __syncthreads();

  // ph6: TMP = M - W1 @ M  (dual global store)
  for (int t = TID; t < 576; t += 256) {
    int i0 = (t / 24) * 4, j0 = (t % 24) * 4;
    f4 acc[4]; acc[0] = acc[1] = acc[2] = acc[3] = f4zero();
    #pragma unroll 4
    for (int k = 0; k < 96; ++k)
      outer4(acc, ld4(&Ws[k][i0]), ld4(&Ms[k][j0]));   // W1[i][k] via symmetry
    float rr[4][4];
    #pragma unroll
    for (int a = 0; a < 4; ++a) {
      f4 mv = ld4(&Ms[i0 + a][j0]);
      f4 tv = make_float4(mv.x - acc[a].x, mv.y - acc[a].y, mv.z - acc[a].z, mv.w - acc[a].w);
      st4(&TMPg[(i0 + a) * 96 + j0], tv);
      rr[a][0] = tv.x; rr[a][1] = tv.y; rr[a][2] = tv.z; rr[a][3] = tv.w;
    }
    #pragma unroll
    for (int b = 0; b < 4; ++b)
      st4(&TMPt[(j0 + b) * 96 + i0], make_float4(rr[0][b], rr[1][b], rr[2][b], rr[3][b]));
  }
  __syncthreads();

  // ph7: M2 = TMP - TMP @ W1^T  -> Ms
  for (int t = TID; t < 576; t += 256) {
    int i0 = (t / 24) * 4, j0 = (t % 24) * 4;
    f4 acc[4]; acc[0] = acc[1] = acc[2] = acc[3] = f4zero();
    #pragma unroll 4
    for (int k = 0; k < 96; ++k)
      outer4(acc, ld4(&TMPt[k * 96 + i0]), ld4(&Ws[k][j0]));
    #pragma unroll
    for (int a = 0; a < 4; ++a) {
      f4 g = ld4(&TMPg[(i0 + a) * 96 + j0]);
      st4(&Ms[i0 + a][j0], make_float4(g.x - acc[a].x, g.y - acc[a].y,
                                       g.z - acc[a].z, g.w - acc[a].w));
    }
  }
  __syncthreads();

  // ph8: C0_2 = C2 - W1 @ C2  -> MAs/MAt (96x16)
  if (TID < 96) {
    int i0 = (TID / 4) * 4, c0 = (TID % 4) * 4;
    f4 acc[4]; acc[0] = acc[1] = acc[2] = acc[3] = f4zero();
    #pragma unroll 4
    for (int k = 0; k < 96; ++k)
      outer4(acc, ld4(&Ws[k][i0]), ld4(&C48[k * 48 + 32 + c0]));
    f4 res[4];
    #pragma unroll
    for (int a = 0; a < 4; ++a) {
      f4 cv = ld4(&C48[(i0 + a) * 48 + 32 + c0]);
      res[a] = make_float4(cv.x - acc[a].x, cv.y - acc[a].y, cv.z - acc[a].z, cv.w - acc[a].w);
    }
    store_dual(MAs, MAt, i0, c0, res);
  }
  __syncthreads();

  // ph9: aug = [G02 | I16]
  if (TID < 64) {
    int e = TID * 8; int i = e / 32, j = e % 32;
    #pragma unroll
    for (int u = 0; u < 8; ++u) {
      int jj = j + u;
      aug[i][jj] = (jj < 16) ? G0[1024 + i * 16 + jj] : ((jj - 16 == i) ? 1.f : 0.f);
    }
  }
  gauss_jordan(aug, colbuf, 16, 32);                           // K02
  mm_dual(&MAt[0][0], 100, &aug[0][16], 64, 16, 4, As, Ast);   // A2 = C0_2 @ K02
  __syncthreads();

  // partition 2: 14 recursions, r = 16
  for (int it = 0; it < 14; ++it) {
    mm_dual(&Ms[0][0], 96, &As[0][0], 32, 96, 4, MAs, MAt);
    __syncthreads();
    phase_SG(MAs, As, aug, 16);
    __syncthreads();
    gauss_jordan(aug, colbuf, 16, 32);
    mm_dual(&MAt[0][0], 100, &aug[0][16], 64, 16, 4, As, Ast);
    __syncthreads();
  }

  // W2 = A inv(A^T A) A^T -> Ms
  phase_Gid(As, aug, 16);
  gauss_jordan(aug, colbuf, 16, 32);
  mm_dual(&Ast[0][0], 100, &aug[0][16], 64, 16, 4, MAs, MAt);  // AK2
  __syncthreads();
  phase_W(MAt, Ast, 16, Ms);                                   // W2 -> Ms
  __syncthreads();

  // ph14: T = W1 + W2 - W2 @ W1 -> Tg
  for (int t = TID; t < 576; t += 256) {
    int i0 = (t / 24) * 4, j0 = (t % 24) * 4;
    f4 acc[4]; acc[0] = acc[1] = acc[2] = acc[3] = f4zero();
    #pragma unroll 4
    for (int k = 0; k < 96; ++k)
      outer4(acc, ld4(&Ms[k][i0]), ld4(&Ws[k][j0]));  // W2[i][k], W1[k][j] via symmetry
    #pragma unroll
    for (int a = 0; a < 4; ++a) {
      f4 w1 = ld4(&Ws[i0 + a][j0]);
      f4 w2 = ld4(&Ms[i0 + a][j0]);
      st4(&Tg[(i0 + a) * 96 + j0],
          make_float4(w1.x + w2.x - acc[a].x, w1.y + w2.y - acc[a].y,
                      w1.z + w2.z - acc[a].z, w1.w + w2.w - acc[a].w));
    }
  }
}

// ---------------------------------------------------------------------------
// k4: out = T @ X.  grid (72, 8), block 256 (128 cols / WG).
// ---------------------------------------------------------------------------
__global__ __launch_bounds__(256) void k4_out(
    const float* __restrict__ x, const float* __restrict__ ws,
    float* __restrict__ out) {
  __shared__ __align__(16) float Tt[96][100];  // T transposed (k-major)
  int jb = blockIdx.x, item = blockIdx.y;
  const float* Tg = ws + OFF_TG + (size_t)item * 9216;
  for (int e = TID * 4; e < 9216; e += 1024) {
    f4 v = ld4(&Tg[e]);
    int i = e / 96, k = e % 96;
    Tt[k][i] = v.x; Tt[k + 1][i] = v.y; Tt[k + 2][i] = v.z; Tt[k + 3][i] = v.w;
  }
  __syncthreads();

  int jq = (TID % 32) * 4, ig = TID / 32;
  int i0 = ig * 12;
  int col = jb * 128 + jq;
  const float* X = x + (size_t)item * 96 * 9216;
  f4 acc[12];
  #pragma unroll
  for (int a = 0; a < 12; ++a) acc[a] = f4zero();

  for (int k = 0; k < 96; ++k) {
    f4 xv = ld4(&X[(size_t)k * 9216 + col]);
    f4 t0 = ld4(&Tt[k][i0]), t1 = ld4(&Tt[k][i0 + 4]), t2 = ld4(&Tt[k][i0 + 8]);
    fma4(acc[0], t0.x, xv); fma4(acc[1], t0.y, xv); fma4(acc[2], t0.z, xv); fma4(acc[3], t0.w, xv);
    fma4(acc[4], t1.x, xv); fma4(acc[5], t1.y, xv); fma4(acc[6], t1.z, xv); fma4(acc[7], t1.w, xv);
    fma4(acc[8], t2.x, xv); fma4(acc[9], t2.y, xv); fma4(acc[10], t2.z, xv); fma4(acc[11], t2.w, xv);
  }
  float* O = out + (size_t)item * 96 * 9216;
  #pragma unroll
  for (int a = 0; a < 12; ++a) st4(&O[(size_t)(i0 + a) * 9216 + col], acc[a]);
}

// ---------------------------------------------------------------------------
extern "C" void kernel_launch(void* const* d_in, const int* in_sizes, int n_in,
                              void* d_out, int out_size, void* d_ws, size_t ws_size,
                              hipStream_t stream) {
  (void)in_sizes; (void)n_in; (void)out_size; (void)ws_size;
  const float* x   = (const float*)d_in[0];
  const float* b01 = (const float*)d_in[2];  // B0_1 (9216 x 32)
  const float* b02 = (const float*)d_in[4];  // B0_2 (9216 x 16)
  float* out = (float*)d_out;
  float* ws  = (float*)d_ws;

  hipMemsetAsync(d_ws, 0, ACC_FLOATS * sizeof(float), stream);
  k1_partials<<<dim3(NCH, 8), 256, 0, stream>>>(x, b01, b02, ws);
  k3_als<<<dim3(8), 256, 0, stream>>>(ws);
  k4_out<<<dim3(72, 8), 256, 0, stream>>>(x, ws, out);
}

// Round 3
// 305.904 us; speedup vs baseline: 2.8326x; 2.8326x over previous
//
#include <hip/hip_runtime.h>

// ---------------------------------------------------------------------------
// MRLR feature extractor, round 3: power-iteration form.
// colspace(A_15) = colspace(M^14 C)  (pinv remixes are colspace-invariant), so
//   W1 = proj(M^14 C1), M2 = (I-W1) M (I-W1), W2 = proj(M2^14 (I-W1)C2),
//   out = (W1 + W2 - W2 W1) X.
// Stages: memset acc; k1: M = X X^T, C = X [B01|B02] (split-K + atomics);
//         k3: per-item chain in LDS (512 thr, 1 WG/item); k4: out = T X.
// ---------------------------------------------------------------------------

#define TID ((int)threadIdx.x)
typedef float4 f4;

#define NCH 24
#define CHK 384   // 9216 / NCH

// workspace layout (float offsets) — total 184,320 floats = 737 KB
#define OFF_MG    0        // 8 * 9216
#define OFF_C48   73728    // 8 * 4608
#define OFF_TG    110592   // 8 * 9216
#define ACC_FLOATS 110592  // zeroed each launch (MG + C48)

#define PSCALE 1.220703125e-4f   // 2^-13

__device__ __forceinline__ f4 ld4(const float* p) { return *(const f4*)p; }
__device__ __forceinline__ void st4(float* p, f4 v) { *(f4*)p = v; }
__device__ __forceinline__ f4 f4zero() { return make_float4(0.f, 0.f, 0.f, 0.f); }
__device__ __forceinline__ f4 add4(f4 a, f4 b) { return make_float4(a.x+b.x, a.y+b.y, a.z+b.z, a.w+b.w); }
__device__ __forceinline__ f4 sub4(f4 a, f4 b) { return make_float4(a.x-b.x, a.y-b.y, a.z-b.z, a.w-b.w); }
__device__ __forceinline__ f4 scl4(f4 a, float s) { return make_float4(a.x*s, a.y*s, a.z*s, a.w*s); }
__device__ __forceinline__ void fma4(f4& a, float s, f4 v) {
  a.x = fmaf(s, v.x, a.x); a.y = fmaf(s, v.y, a.y);
  a.z = fmaf(s, v.z, a.z); a.w = fmaf(s, v.w, a.w);
}
__device__ __forceinline__ void outer4(f4* acc, f4 u, f4 v) {
  fma4(acc[0], u.x, v); fma4(acc[1], u.y, v);
  fma4(acc[2], u.z, v); fma4(acc[3], u.w, v);
}

// ---------------------------------------------------------------------------
// k1: split-K partial outer products, accumulated via f32 atomics.
// grid (NCH, 8), block 256.  144 M-tiles + 72 C-tiles (8x8 each).
// ---------------------------------------------------------------------------
__global__ __launch_bounds__(256) void k1_partials(
    const float* __restrict__ x, const float* __restrict__ b01,
    const float* __restrict__ b02, float* __restrict__ ws) {
  __shared__ __align__(16) float Xst[64][100];  // transposed X slab (k-major)
  __shared__ __align__(16) float Bs[64][52];    // [B01 | B02] slab (k-major)
  int kc = blockIdx.x, item = blockIdx.y;
  const float* X = x + (size_t)item * 96 * 9216;

  const float* ap = nullptr; const float* bp = nullptr;
  int asr = 0, bsr = 0, os = 0;
  float* op = nullptr;
  bool active = false;
  {
    int t = TID;
    if (t < 144) {
      int i0 = (t / 12) * 8, j0 = (t % 12) * 8;
      ap = &Xst[0][i0]; asr = 100; bp = &Xst[0][j0]; bsr = 100;
      op = ws + OFF_MG + (size_t)item * 9216 + i0 * 96 + j0;
      os = 96; active = true;
    } else if (t < 216) {
      int u = t - 144; int i0 = (u / 6) * 8, c0 = (u % 6) * 8;
      ap = &Xst[0][i0]; asr = 100; bp = &Bs[0][c0]; bsr = 52;
      op = ws + OFF_C48 + (size_t)item * 4608 + i0 * 48 + c0;
      os = 48; active = true;
    }
  }

  f4 acc[8][2];
  #pragma unroll
  for (int a = 0; a < 8; ++a) { acc[a][0] = f4zero(); acc[a][1] = f4zero(); }

  for (int sc = 0; sc < 6; ++sc) {
    int k0 = kc * CHK + sc * 64;
    __syncthreads();
    for (int e = TID; e < 1536; e += 256) {          // X slab, transposed store
      int i = e / 16, kq = (e % 16) * 4;
      f4 v = ld4(&X[(size_t)i * 9216 + k0 + kq]);
      Xst[kq][i] = v.x; Xst[kq + 1][i] = v.y; Xst[kq + 2][i] = v.z; Xst[kq + 3][i] = v.w;
    }
    for (int e = TID; e < 512; e += 256) {           // B01 slab
      int kk = e / 8, cq = (e % 8) * 4;
      st4(&Bs[kk][cq], ld4(&b01[(size_t)(k0 + kk) * 32 + cq]));
    }
    for (int e = TID; e < 256; e += 256) {           // B02 slab
      int kk = e / 4, cq = (e % 4) * 4;
      st4(&Bs[kk][32 + cq], ld4(&b02[(size_t)(k0 + kk) * 16 + cq]));
    }
    __syncthreads();
    if (active) {
      for (int kk = 0; kk < 64; ++kk) {
        const float* ar = ap + kk * asr;
        const float* br = bp + kk * bsr;
        f4 b0v = ld4(br), b1v = ld4(br + 4);
        f4 a0v = ld4(ar), a1v = ld4(ar + 4);
        float aa[8] = {a0v.x, a0v.y, a0v.z, a0v.w, a1v.x, a1v.y, a1v.z, a1v.w};
        #pragma unroll
        for (int a = 0; a < 8; ++a) { fma4(acc[a][0], aa[a], b0v); fma4(acc[a][1], aa[a], b1v); }
      }
    }
  }
  if (active) {
    #pragma unroll
    for (int a = 0; a < 8; ++a) {
      float vals[8] = {acc[a][0].x, acc[a][0].y, acc[a][0].z, acc[a][0].w,
                       acc[a][1].x, acc[a][1].y, acc[a][1].z, acc[a][1].w};
      #pragma unroll
      for (int u = 0; u < 8; ++u) atomicAdd(op + a * os + u, vals[u]);
    }
  }
}

// ---------------------------------------------------------------------------
// Unnormalized Gauss-Jordan on aug[r][0:C]; solves L Z = RHS (L=aug[:,0:r],
// RHS=aug[:,r:C]); Z left in aug[:,r:C].  Double-buffered pivot-column cache
// avoids the read/write race; eliminated columns zeroed exactly.
// Call with ALL threads (barriers inside).
// ---------------------------------------------------------------------------
__device__ void gauss_jordan(float (*aug)[64], float (*colbuf)[32], int r, int C) {
  int noct = C >> 3;
  int nthr = r * noct;
  __syncthreads();
  if (TID < r) colbuf[0][TID] = aug[TID][0];
  for (int c = 0; c < r; ++c) {
    __syncthreads();
    if (TID < nthr) {
      int i = TID / noct, j0 = (TID % noct) * 8;
      const float* cb = colbuf[c & 1];
      float f = cb[i] / cb[c];
      int nc = c + 1;
      bool own = (nc < r) && (nc >= j0) && (nc < j0 + 8);
      if (i != c) {
        f4 p0 = ld4(&aug[c][j0]), p1 = ld4(&aug[c][j0 + 4]);
        f4 v0 = ld4(&aug[i][j0]), v1 = ld4(&aug[i][j0 + 4]);
        float pr[8] = {p0.x, p0.y, p0.z, p0.w, p1.x, p1.y, p1.z, p1.w};
        float vv[8] = {v0.x, v0.y, v0.z, v0.w, v1.x, v1.y, v1.z, v1.w};
        #pragma unroll
        for (int u = 0; u < 8; ++u)
          vv[u] = (j0 + u == c) ? 0.f : fmaf(-f, pr[u], vv[u]);
        st4(&aug[i][j0], make_float4(vv[0], vv[1], vv[2], vv[3]));
        st4(&aug[i][j0 + 4], make_float4(vv[4], vv[5], vv[6], vv[7]));
        if (own) colbuf[nc & 1][i] = vv[nc - j0];
      } else {
        if (own) colbuf[nc & 1][i] = aug[c][nc];
      }
    }
  }
  __syncthreads();
  int w = C - r;
  int nq = r * (w >> 2);
  if (TID < nq) {
    int i = TID / (w >> 2), jq = (TID % (w >> 2)) * 4;
    float d = aug[i][i];
    f4 z = ld4(&aug[i][r + jq]);
    z.x /= d; z.y /= d; z.z /= d; z.w /= d;
    st4(&aug[i][r + jq], z);
  }
  __syncthreads();
}

// ---------------------------------------------------------------------------
// k3: per-item chain.  grid (8), block 512.  LDS ~140 KB, 1 WG/CU.
// ---------------------------------------------------------------------------
__global__ __launch_bounds__(512) void k3_als(float* __restrict__ ws) {
  __shared__ __align__(16) float Ms[96][96];    // M, then M2, then W2
  __shared__ __align__(16) float Ws[96][96];    // W1
  __shared__ __align__(16) float TMPs[9216];    // scratch: partials / Pt,AKt / TMP
  __shared__ __align__(16) float P[96][32];     // P ping (C1 -> P1 -> C2' -> P2)
  __shared__ __align__(16) float Q[96][32];     // P pong / AK / C2
  __shared__ __align__(16) float aug[32][64];
  __shared__ __align__(16) float colbuf[2][32];

  int item = blockIdx.x;
  const float* Mg  = ws + OFF_MG  + (size_t)item * 9216;
  const float* C48 = ws + OFF_C48 + (size_t)item * 4608;
  float* Tg = ws + OFF_TG + (size_t)item * 9216;

  // ph0: load M and C1
  for (int e = TID * 4; e < 9216; e += 2048) st4(&Ms[0][0] + e, ld4(&Mg[e]));
  for (int t = TID; t < 768; t += 512) {
    int i = t >> 3, c = (t & 7) * 4;
    st4(&P[i][c], ld4(&C48[i * 48 + c]));
  }
  __syncthreads();

  // ---- partition 1: 14 power steps, P <- (M P) * 2^-13  (96x32, ksplit2)
  {
    float* src = &P[0][0];
    float* dst = &Q[0][0];
    for (int it = 0; it < 14; ++it) {
      f4 acc[4]; acc[0] = acc[1] = acc[2] = acc[3] = f4zero();
      int ch = TID / 192, tt = TID % 192;
      int i0 = (tt >> 3) * 4, c0 = (tt & 7) * 4;
      if (TID < 384) {
        int kb = ch * 48;
        #pragma unroll 4
        for (int k = kb; k < kb + 48; ++k)
          outer4(acc, ld4(&Ms[k][i0]), ld4(src + k * 32 + c0));  // M sym
        if (ch == 1) {
          #pragma unroll
          for (int a = 0; a < 4; ++a) st4(&TMPs[tt * 16 + a * 4], acc[a]);
        }
      }
      __syncthreads();
      if (TID < 192) {
        #pragma unroll
        for (int a = 0; a < 4; ++a) {
          f4 o = ld4(&TMPs[tt * 16 + a * 4]);
          st4(dst + (i0 + a) * 32 + c0, scl4(add4(acc[a], o), PSCALE));
        }
      }
      __syncthreads();
      float* tm = src; src = dst; dst = tm;
    }
  }
  // P1 now in P (14 steps: last write was into P)

  // ---- Gram1 = P^T P (32x32, ksplit4) + identity -> aug
  {
    f4 acc[4]; acc[0] = acc[1] = acc[2] = acc[3] = f4zero();
    int ch = TID / 64, t = TID % 64;
    int a0 = (t >> 3) * 4, b0 = (t & 7) * 4;
    if (TID < 256) {
      int kb = ch * 24;
      #pragma unroll 4
      for (int k = kb; k < kb + 24; ++k)
        outer4(acc, ld4(&P[k][a0]), ld4(&P[k][b0]));
      if (ch > 0) {
        #pragma unroll
        for (int a = 0; a < 4; ++a) st4(&TMPs[(ch - 1) * 1024 + t * 16 + a * 4], acc[a]);
      }
    } else if (TID < 288) {
      int i = TID - 256;
      for (int j = 0; j < 32; j += 4)
        st4(&aug[i][32 + j], make_float4(i == j ? 1.f : 0.f, i == j + 1 ? 1.f : 0.f,
                                         i == j + 2 ? 1.f : 0.f, i == j + 3 ? 1.f : 0.f));
    }
    __syncthreads();
    if (TID < 64) {
      #pragma unroll
      for (int a = 0; a < 4; ++a) {
        f4 s = acc[a];
        #pragma unroll
        for (int p = 0; p < 3; ++p) s = add4(s, ld4(&TMPs[p * 1024 + t * 16 + a * 4]));
        st4(&aug[a0 + a][b0], s);
      }
    }
  }
  gauss_jordan(aug, colbuf, 32, 64);   // K1 = inv(G1) in aug[:,32:64]

  // ---- AK = P K1 -> Q (96x32, msplit2)
  {
    f4 acc[4]; acc[0] = acc[1] = acc[2] = acc[3] = f4zero();
    int ch = TID / 192, tt = TID % 192;
    int i0 = (tt >> 3) * 4, c0 = (tt & 7) * 4;
    if (TID < 384) {
      int mb = ch * 16;
      #pragma unroll 4
      for (int m = mb; m < mb + 16; ++m) {
        f4 z = ld4(&aug[m][32 + c0]);
        fma4(acc[0], P[i0 + 0][m], z); fma4(acc[1], P[i0 + 1][m], z);
        fma4(acc[2], P[i0 + 2][m], z); fma4(acc[3], P[i0 + 3][m], z);
      }
      if (ch == 1) {
        #pragma unroll
        for (int a = 0; a < 4; ++a) st4(&TMPs[tt * 16 + a * 4], acc[a]);
      }
    }
    __syncthreads();
    if (TID < 192) {
      #pragma unroll
      for (int a = 0; a < 4; ++a) {
        f4 o = ld4(&TMPs[tt * 16 + a * 4]);
        st4(&Q[i0 + a][c0], add4(acc[a], o));
      }
    }
  }
  __syncthreads();

  // ---- transpose Pt -> TMPs[0..3199], AKt -> TMPs[3200..6399]  ([32][100])
  for (int t = TID; t < 1536; t += 512) {
    if (t < 768) {
      int i = t >> 3, c0 = (t & 7) * 4; f4 v = ld4(&P[i][c0]);
      TMPs[(c0 + 0) * 100 + i] = v.x; TMPs[(c0 + 1) * 100 + i] = v.y;
      TMPs[(c0 + 2) * 100 + i] = v.z; TMPs[(c0 + 3) * 100 + i] = v.w;
    } else {
      int u = t - 768; int i = u >> 3, c0 = (u & 7) * 4; f4 v = ld4(&Q[i][c0]);
      TMPs[3200 + (c0 + 0) * 100 + i] = v.x; TMPs[3200 + (c0 + 1) * 100 + i] = v.y;
      TMPs[3200 + (c0 + 2) * 100 + i] = v.z; TMPs[3200 + (c0 + 3) * 100 + i] = v.w;
    }
  }
  __syncthreads();

  // ---- W1 = AK P^T -> Ws (96x96)
  for (int t = TID; t < 576; t += 512) {
    int i0 = (t / 24) * 4, j0 = (t % 24) * 4;
    f4 acc[4]; acc[0] = acc[1] = acc[2] = acc[3] = f4zero();
    #pragma unroll 4
    for (int c = 0; c < 32; ++c)
      outer4(acc, ld4(&TMPs[3200 + c * 100 + i0]), ld4(&TMPs[c * 100 + j0]));
    #pragma unroll
    for (int a = 0; a < 4; ++a) st4(&Ws[i0 + a][j0], acc[a]);
  }
  __syncthreads();

  // ---- C2 -> Q[:,0:16]
  for (int t = TID; t < 384; t += 512) {
    int i = t >> 2, c0 = (t & 3) * 4;
    st4(&Q[i][c0], ld4(&C48[i * 48 + 32 + c0]));
  }
  __syncthreads();

  // ---- C2' = C2 - W1 C2 -> P[:,0:16]  (ksplit2)
  {
    f4 acc[4]; acc[0] = acc[1] = acc[2] = acc[3] = f4zero();
    int ch = TID / 96, tt = TID % 96;
    int i0 = (tt >> 2) * 4, c0 = (tt & 3) * 4;
    if (TID < 192) {
      int kb = ch * 48;
      #pragma unroll 4
      for (int k = kb; k < kb + 48; ++k)
        outer4(acc, ld4(&Ws[k][i0]), ld4(&Q[k][c0]));   // W1 sym
      if (ch == 1) {
        #pragma unroll
        for (int a = 0; a < 4; ++a) st4(&TMPs[tt * 16 + a * 4], acc[a]);
      }
    }
    __syncthreads();
    if (TID < 96) {
      #pragma unroll
      for (int a = 0; a < 4; ++a) {
        f4 o = ld4(&TMPs[tt * 16 + a * 4]);
        f4 cv = ld4(&Q[i0 + a][c0]);
        st4(&P[i0 + a][c0], sub4(cv, add4(acc[a], o)));
      }
    }
  }
  __syncthreads();

  // ---- TMP = M - W1 M -> TMPs (96x96)
  for (int t = TID; t < 576; t += 512) {
    int i0 = (t / 24) * 4, j0 = (t % 24) * 4;
    f4 acc[4]; acc[0] = acc[1] = acc[2] = acc[3] = f4zero();
    #pragma unroll 4
    for (int k = 0; k < 96; ++k)
      outer4(acc, ld4(&Ws[k][i0]), ld4(&Ms[k][j0]));    // W1[i][k] via symmetry
    #pragma unroll
    for (int a = 0; a < 4; ++a) {
      f4 mv = ld4(&Ms[i0 + a][j0]);
      st4(&TMPs[(i0 + a) * 96 + j0], sub4(mv, acc[a]));
    }
  }
  __syncthreads();

  // ---- M2 = TMP - TMP W1 -> Ms  (row-broadcast reads of TMP)
  for (int t = TID; t < 576; t += 512) {
    int i0 = (t / 24) * 4, j0 = (t % 24) * 4;
    f4 acc[4]; acc[0] = acc[1] = acc[2] = acc[3] = f4zero();
    #pragma unroll 4
    for (int k = 0; k < 96; ++k) {
      f4 wv = ld4(&Ws[k][j0]);
      fma4(acc[0], TMPs[(i0 + 0) * 96 + k], wv);
      fma4(acc[1], TMPs[(i0 + 1) * 96 + k], wv);
      fma4(acc[2], TMPs[(i0 + 2) * 96 + k], wv);
      fma4(acc[3], TMPs[(i0 + 3) * 96 + k], wv);
    }
    #pragma unroll
    for (int a = 0; a < 4; ++a) {
      f4 tv = ld4(&TMPs[(i0 + a) * 96 + j0]);
      st4(&Ms[i0 + a][j0], sub4(tv, acc[a]));
    }
  }
  __syncthreads();

  // ---- partition 2: 14 power steps, P2 <- (M2 P2) * 2^-13  (96x16, ksplit4)
  {
    float* src = &P[0][0];
    float* dst = &Q[0][0];
    for (int it = 0; it < 14; ++it) {
      f4 acc[4]; acc[0] = acc[1] = acc[2] = acc[3] = f4zero();
      int ch = TID / 96, tt = TID % 96;
      int i0 = (tt >> 2) * 4, c0 = (tt & 3) * 4;
      if (TID < 384) {
        int kb = ch * 24;
        #pragma unroll 4
        for (int k = kb; k < kb + 24; ++k)
          outer4(acc, ld4(&Ms[k][i0]), ld4(src + k * 32 + c0));  // M2 sym
        #pragma unroll
        for (int a = 0; a < 4; ++a) st4(&TMPs[ch * 1536 + tt * 16 + a * 4], acc[a]);
      }
      __syncthreads();
      if (TID < 384) {
        int t2 = TID >> 2, a = TID & 3;
        int row = (t2 >> 2) * 4 + a, col = (t2 & 3) * 4;
        f4 s = f4zero();
        #pragma unroll
        for (int c2 = 0; c2 < 4; ++c2) s = add4(s, ld4(&TMPs[c2 * 1536 + t2 * 16 + a * 4]));
        st4(dst + row * 32 + col, scl4(s, PSCALE));
      }
      __syncthreads();
      float* tm = src; src = dst; dst = tm;
    }
  }
  // P2 in P[:,0:16]

  // ---- Gram2 = P2^T P2 (16x16, ksplit4) + identity -> aug
  {
    f4 acc[4]; acc[0] = acc[1] = acc[2] = acc[3] = f4zero();
    int ch = TID / 16, t = TID % 16;
    int a0 = (t >> 2) * 4, b0 = (t & 3) * 4;
    if (TID < 64) {
      int kb = ch * 24;
      #pragma unroll 4
      for (int k = kb; k < kb + 24; ++k)
        outer4(acc, ld4(&P[k][a0]), ld4(&P[k][b0]));
      if (ch > 0) {
        #pragma unroll
        for (int a = 0; a < 4; ++a) st4(&TMPs[(ch - 1) * 256 + t * 16 + a * 4], acc[a]);
      }
    } else if (TID < 80) {
      int i = TID - 64;
      for (int j = 0; j < 16; j += 4)
        st4(&aug[i][16 + j], make_float4(i == j ? 1.f : 0.f, i == j + 1 ? 1.f : 0.f,
                                         i == j + 2 ? 1.f : 0.f, i == j + 3 ? 1.f : 0.f));
    }
    __syncthreads();
    if (TID < 16) {
      #pragma unroll
      for (int a = 0; a < 4; ++a) {
        f4 s = acc[a];
        #pragma unroll
        for (int p = 0; p < 3; ++p) s = add4(s, ld4(&TMPs[p * 256 + t * 16 + a * 4]));
        st4(&aug[a0 + a][b0], s);
      }
    }
  }
  gauss_jordan(aug, colbuf, 16, 32);   // K2 in aug[:,16:32]

  // ---- AK2 = P2 K2 -> Q[:,0:16]
  if (TID < 96) {
    int i0 = (TID >> 2) * 4, c0 = (TID & 3) * 4;
    f4 acc[4]; acc[0] = acc[1] = acc[2] = acc[3] = f4zero();
    #pragma unroll 4
    for (int m = 0; m < 16; ++m) {
      f4 z = ld4(&aug[m][16 + c0]);
      fma4(acc[0], P[i0 + 0][m], z); fma4(acc[1], P[i0 + 1][m], z);
      fma4(acc[2], P[i0 + 2][m], z); fma4(acc[3], P[i0 + 3][m], z);
    }
    #pragma unroll
    for (int a = 0; a < 4; ++a) st4(&Q[i0 + a][c0], acc[a]);
  }
  __syncthreads();

  // ---- transpose P2t -> TMPs[0..1599], AK2t -> TMPs[1600..3199]  ([16][100])
  for (int t = TID; t < 768; t += 512) {
    if (t < 384) {
      int i = t >> 2, c0 = (t & 3) * 4; f4 v = ld4(&P[i][c0]);
      TMPs[(c0 + 0) * 100 + i] = v.x; TMPs[(c0 + 1) * 100 + i] = v.y;
      TMPs[(c0 + 2) * 100 + i] = v.z; TMPs[(c0 + 3) * 100 + i] = v.w;
    } else {
      int u = t - 384; int i = u >> 2, c0 = (u & 3) * 4; f4 v = ld4(&Q[i][c0]);
      TMPs[1600 + (c0 + 0) * 100 + i] = v.x; TMPs[1600 + (c0 + 1) * 100 + i] = v.y;
      TMPs[1600 + (c0 + 2) * 100 + i] = v.z; TMPs[1600 + (c0 + 3) * 100 + i] = v.w;
    }
  }
  __syncthreads();

  // ---- W2 = AK2 P2^T -> Ms (M2 dead)
  for (int t = TID; t < 576; t += 512) {
    int i0 = (t / 24) * 4, j0 = (t % 24) * 4;
    f4 acc[4]; acc[0] = acc[1] = acc[2] = acc[3] = f4zero();
    #pragma unroll 4
    for (int c = 0; c < 16; ++c)
      outer4(acc, ld4(&TMPs[1600 + c * 100 + i0]), ld4(&TMPs[c * 100 + j0]));
    #pragma unroll
    for (int a = 0; a < 4; ++a) st4(&Ms[i0 + a][j0], acc[a]);
  }
  __syncthreads();

  // ---- T = W1 + W2 - W2 W1 -> Tg
  for (int t = TID; t < 576; t += 512) {
    int i0 = (t / 24) * 4, j0 = (t % 24) * 4;
    f4 acc[4]; acc[0] = acc[1] = acc[2] = acc[3] = f4zero();
    #pragma unroll 4
    for (int k = 0; k < 96; ++k)
      outer4(acc, ld4(&Ms[k][i0]), ld4(&Ws[k][j0]));   // W2[i][k] via symmetry
    #pragma unroll
    for (int a = 0; a < 4; ++a) {
      f4 w1 = ld4(&Ws[i0 + a][j0]);
      f4 w2 = ld4(&Ms[i0 + a][j0]);
      st4(&Tg[(i0 + a) * 96 + j0], sub4(add4(w1, w2), acc[a]));
    }
  }
}

// ---------------------------------------------------------------------------
// k4: out = T @ X.  grid (72, 8), block 256 (128 cols / WG).
// ---------------------------------------------------------------------------
__global__ __launch_bounds__(256) void k4_out(
    const float* __restrict__ x, const float* __restrict__ ws,
    float* __restrict__ out) {
  __shared__ __align__(16) float Tt[96][100];  // T transposed (k-major)
  int jb = blockIdx.x, item = blockIdx.y;
  const float* Tg = ws + OFF_TG + (size_t)item * 9216;
  for (int e = TID * 4; e < 9216; e += 1024) {
    f4 v = ld4(&Tg[e]);
    int i = e / 96, k = e % 96;
    Tt[k][i] = v.x; Tt[k + 1][i] = v.y; Tt[k + 2][i] = v.z; Tt[k + 3][i] = v.w;
  }
  __syncthreads();

  int jq = (TID % 32) * 4, ig = TID / 32;
  int i0 = ig * 12;
  int col = jb * 128 + jq;
  const float* X = x + (size_t)item * 96 * 9216;
  f4 acc[12];
  #pragma unroll
  for (int a = 0; a < 12; ++a) acc[a] = f4zero();

  for (int k = 0; k < 96; ++k) {
    f4 xv = ld4(&X[(size_t)k * 9216 + col]);
    f4 t0 = ld4(&Tt[k][i0]), t1 = ld4(&Tt[k][i0 + 4]), t2 = ld4(&Tt[k][i0 + 8]);
    fma4(acc[0], t0.x, xv); fma4(acc[1], t0.y, xv); fma4(acc[2], t0.z, xv); fma4(acc[3], t0.w, xv);
    fma4(acc[4], t1.x, xv); fma4(acc[5], t1.y, xv); fma4(acc[6], t1.z, xv); fma4(acc[7], t1.w, xv);
    fma4(acc[8], t2.x, xv); fma4(acc[9], t2.y, xv); fma4(acc[10], t2.z, xv); fma4(acc[11], t2.w, xv);
  }
  float* O = out + (size_t)item * 96 * 9216;
  #pragma unroll
  for (int a = 0; a < 12; ++a) st4(&O[(size_t)(i0 + a) * 9216 + col], acc[a]);
}

// ---------------------------------------------------------------------------
extern "C" void kernel_launch(void* const* d_in, const int* in_sizes, int n_in,
                              void* d_out, int out_size, void* d_ws, size_t ws_size,
                              hipStream_t stream) {
  (void)in_sizes; (void)n_in; (void)out_size; (void)ws_size;
  const float* x   = (const float*)d_in[0];
  const float* b01 = (const float*)d_in[2];  // B0_1 (9216 x 32)
  const float* b02 = (const float*)d_in[4];  // B0_2 (9216 x 16)
  float* out = (float*)d_out;
  float* ws  = (float*)d_ws;

  hipMemsetAsync(d_ws, 0, (size_t)ACC_FLOATS * sizeof(float), stream);
  k1_partials<<<dim3(NCH, 8), 256, 0, stream>>>(x, b01, b02, ws);
  k3_als<<<dim3(8), 512, 0, stream>>>(ws);
  k4_out<<<dim3(72, 8), 256, 0, stream>>>(x, ws, out);
}

// Round 4
// 246.914 us; speedup vs baseline: 3.5093x; 1.2389x over previous
//
#include <hip/hip_runtime.h>

// ---------------------------------------------------------------------------
// MRLR feature extractor, round 4.
//   W1 = proj(M^14 C1) via repeated squaring (S1=M^2*2^-27, S2=S1^2, S3=S2^2,
//   P = S3*S2*S1*C1);  M2 = (I-W1)M(I-W1);  W2 = proj(M2^14 C2');
//   T = W1 + W2  (W2*W1 == 0 exactly);  out = T X.
// k1: triangle M = X X^T (packed upper tiles) + C = X[B01|B02], split-K
//     partials, k-parity split inside WG, no atomics.  grid(32,8) x 512.
// k2: reduce 32 partials (coalesced).  k3: per-item chain in LDS, grid(8)x512.
// k4: out = T X.
// ---------------------------------------------------------------------------

#define TID ((int)threadIdx.x)
typedef float4 f4;

#define NCH 32
#define CHK 288            // 9216/32, staged as 6 sub-chunks of 48
#define PBLK 9600          // per-WG partial block: 78*64 M-tiles + 96*48 C
#define COFF 4992          // C offset inside block (78*64)

// workspace layout (float offsets) — total 2,608,128 floats = 10.43 MB
#define OFF_PART 0                 // 8*32*9600
#define OFF_MGP  2457600           // 8*9600   (packed upper-M + C)
#define OFF_TG   2534400           // 8*9216
#define SC27 (1.0f/134217728.0f)   // 2^-27

__device__ __forceinline__ f4 ld4(const float* p) { return *(const f4*)p; }
__device__ __forceinline__ void st4(float* p, f4 v) { *(f4*)p = v; }
__device__ __forceinline__ f4 f4zero() { return make_float4(0.f,0.f,0.f,0.f); }
__device__ __forceinline__ f4 add4(f4 a, f4 b){ return make_float4(a.x+b.x,a.y+b.y,a.z+b.z,a.w+b.w); }
__device__ __forceinline__ f4 sub4(f4 a, f4 b){ return make_float4(a.x-b.x,a.y-b.y,a.z-b.z,a.w-b.w); }
__device__ __forceinline__ f4 scl4(f4 a, float s){ return make_float4(a.x*s,a.y*s,a.z*s,a.w*s); }
__device__ __forceinline__ void fma4(f4& a, float s, f4 v) {
  a.x = fmaf(s,v.x,a.x); a.y = fmaf(s,v.y,a.y); a.z = fmaf(s,v.z,a.z); a.w = fmaf(s,v.w,a.w);
}
__device__ __forceinline__ float getc(f4 v, int u) {
  return u==0 ? v.x : (u==1 ? v.y : (u==2 ? v.z : v.w));
}
__device__ __forceinline__ float dot4(f4 a, f4 b, float acc) {
  acc = fmaf(a.x,b.x,acc); acc = fmaf(a.y,b.y,acc);
  acc = fmaf(a.z,b.z,acc); acc = fmaf(a.w,b.w,acc); return acc;
}
// triangle tile index -> (ti,tj), ti<=tj, 12x12 tile grid, 78 tiles
__device__ __forceinline__ void trimap(int t, int& ti, int& tj) {
  int rem = t; ti = 0;
  #pragma unroll
  for (int r = 0; r < 12; ++r) { int w = 12 - r; if (rem < w) { ti = r; break; } rem -= w; }
  tj = ti + rem;
}

// ---------------------------------------------------------------------------
// k1: grid (NCH, 8), block 512.
// tasks: 300 = 2 k-parity halves x (78 tri-M + 72 C) 8x8 tiles.
// ---------------------------------------------------------------------------
__global__ __launch_bounds__(512) void k1_partials(
    const float* __restrict__ x, const float* __restrict__ b01,
    const float* __restrict__ b02, float* __restrict__ ws) {
  __shared__ __align__(16) float Xst[48][100];   // transposed X slab (k-major)
  __shared__ __align__(16) float Bs[48][52];     // [B01|B02] slab (k-major)
  __shared__ __align__(16) float red[9600];      // k-parity reduction
  int kc = blockIdx.x, item = blockIdx.y;
  const float* X = x + (size_t)item * 96 * 9216;
  float* base = ws + OFF_PART + (size_t)(item * NCH + kc) * PBLK;

  int t = TID, kh = 0, tt = 0;
  const float* ap = nullptr; const float* bp = nullptr;
  float* op = nullptr; int os = 0; bool active = (t < 300);
  if (active) {
    kh = t / 150; tt = t % 150;
    if (tt < 78) {
      int ti, tj; trimap(tt, ti, tj);
      ap = &Xst[0][ti*8]; bp = &Xst[0][tj*8];
      op = base + tt*64; os = 8;
    } else {
      int u = tt - 78; int i0 = (u/6)*8, c0 = (u%6)*8;
      ap = &Xst[0][i0]; bp = &Bs[0][c0];
      op = base + COFF + i0*48 + c0; os = 48;
    }
  }

  f4 acc[8][2];
  #pragma unroll
  for (int a = 0; a < 8; ++a) { acc[a][0] = f4zero(); acc[a][1] = f4zero(); }

  for (int sc = 0; sc < 6; ++sc) {
    int k0 = kc * CHK + sc * 48;
    __syncthreads();
    for (int e = TID; e < 1152; e += 512) {          // X slab transposed
      int i = e / 12, kq = (e % 12) * 4;
      f4 v = ld4(&X[(size_t)i * 9216 + k0 + kq]);
      Xst[kq][i] = v.x; Xst[kq+1][i] = v.y; Xst[kq+2][i] = v.z; Xst[kq+3][i] = v.w;
    }
    for (int e = TID; e < 384; e += 512) {           // B01
      int kk = e / 8, cq = (e % 8) * 4;
      st4(&Bs[kk][cq], ld4(&b01[(size_t)(k0 + kk) * 32 + cq]));
    }
    for (int e = TID; e < 192; e += 512) {           // B02
      int kk = e / 4, cq = (e % 4) * 4;
      st4(&Bs[kk][32+cq], ld4(&b02[(size_t)(k0 + kk) * 16 + cq]));
    }
    __syncthreads();
    if (active) {
      const float* ar = ap + kh * 100;
      const float* br = bp + kh * ((tt < 78) ? 100 : 52);
      int astep = 200, bstep = (tt < 78) ? 200 : 104;
      f4 ca0 = ld4(ar), ca1 = ld4(ar+4), cb0 = ld4(br), cb1 = ld4(br+4);
      for (int kk = kh; kk < 48; kk += 2) {
        f4 na0 = ca0, na1 = ca1, nb0 = cb0, nb1 = cb1;
        if (kk + 2 < 48) {
          ar += astep; br += bstep;
          na0 = ld4(ar); na1 = ld4(ar+4); nb0 = ld4(br); nb1 = ld4(br+4);
        }
        float aa[8] = {ca0.x,ca0.y,ca0.z,ca0.w,ca1.x,ca1.y,ca1.z,ca1.w};
        #pragma unroll
        for (int a = 0; a < 8; ++a) { fma4(acc[a][0], aa[a], cb0); fma4(acc[a][1], aa[a], cb1); }
        ca0 = na0; ca1 = na1; cb0 = nb0; cb1 = nb1;
      }
    }
  }
  __syncthreads();
  if (active && kh == 1) {
    #pragma unroll
    for (int a = 0; a < 8; ++a) { st4(&red[tt*64 + a*8], acc[a][0]); st4(&red[tt*64 + a*8 + 4], acc[a][1]); }
  }
  __syncthreads();
  if (active && kh == 0) {
    #pragma unroll
    for (int a = 0; a < 8; ++a) {
      f4 s0 = add4(acc[a][0], ld4(&red[tt*64 + a*8]));
      f4 s1 = add4(acc[a][1], ld4(&red[tt*64 + a*8 + 4]));
      st4(op + a*os, s0); st4(op + a*os + 4, s1);
    }
  }
}

// ---------------------------------------------------------------------------
// k2: reduce NCH partials.  grid 75, block 256: 19200 f4 outputs.
// ---------------------------------------------------------------------------
__global__ __launch_bounds__(256) void k2_reduce(float* __restrict__ ws) {
  int gid = blockIdx.x * 256 + TID;       // < 19200
  int b = gid / 2400, off = (gid % 2400) * 4;
  const float* p = ws + OFF_PART + (size_t)b * NCH * PBLK + off;
  f4 s = f4zero();
  #pragma unroll 8
  for (int c = 0; c < NCH; ++c) s = add4(s, ld4(p + (size_t)c * PBLK));
  st4(&ws[OFF_MGP + (size_t)b * PBLK + off], s);
}

// ---------------------------------------------------------------------------
// k3 helpers
// ---------------------------------------------------------------------------
__device__ void gauss_jordan(float (*aug)[64], float (*colbuf)[32], int r, int C) {
  int noct = C >> 3;
  int nthr = r * noct;
  __syncthreads();
  if (TID < r) colbuf[0][TID] = aug[TID][0];
  for (int c = 0; c < r; ++c) {
    __syncthreads();
    if (TID < nthr) {
      int i = TID / noct, j0 = (TID % noct) * 8;
      const float* cb = colbuf[c & 1];
      float f = cb[i] / cb[c];
      int nc = c + 1;
      bool own = (nc < r) && (nc >= j0) && (nc < j0 + 8);
      if (i != c) {
        f4 p0 = ld4(&aug[c][j0]), p1 = ld4(&aug[c][j0+4]);
        f4 v0 = ld4(&aug[i][j0]), v1 = ld4(&aug[i][j0+4]);
        float pr[8] = {p0.x,p0.y,p0.z,p0.w,p1.x,p1.y,p1.z,p1.w};
        float vv[8] = {v0.x,v0.y,v0.z,v0.w,v1.x,v1.y,v1.z,v1.w};
        #pragma unroll
        for (int u = 0; u < 8; ++u)
          vv[u] = (j0 + u == c) ? 0.f : fmaf(-f, pr[u], vv[u]);
        st4(&aug[i][j0], make_float4(vv[0],vv[1],vv[2],vv[3]));
        st4(&aug[i][j0+4], make_float4(vv[4],vv[5],vv[6],vv[7]));
        if (own) colbuf[nc & 1][i] = vv[nc - j0];
      } else {
        if (own) colbuf[nc & 1][i] = aug[c][nc];
      }
    }
  }
  __syncthreads();
  int w = C - r, nq = r * (w >> 2);
  if (TID < nq) {
    int i = TID / (w >> 2), jq = (TID % (w >> 2)) * 4;
    float d = aug[i][i];
    f4 z = ld4(&aug[i][r + jq]);
    z.x /= d; z.y /= d; z.z /= d; z.w /= d;
    st4(&aug[i][r + jq], z);
  }
  __syncthreads();
}

__device__ __forceinline__ void tile8_step(f4 acc[8][2], const float* u, const float* v) {
  f4 u0 = ld4(u), u1 = ld4(u+4), v0 = ld4(v), v1 = ld4(v+4);
  float aa[8] = {u0.x,u0.y,u0.z,u0.w,u1.x,u1.y,u1.z,u1.w};
  #pragma unroll
  for (int a = 0; a < 8; ++a) { fma4(acc[a][0], aa[a], v0); fma4(acc[a][1], aa[a], v1); }
}

// acc[4][2] += sum_k S[k][i0..+4] (x) Pin[k][c0..c0+8]
__device__ __forceinline__ void app_tile(const float (*S)[96], const float (*Pin)[32],
                                         f4 acc[4][2], int i0, int c0, int ka, int kb) {
  #pragma unroll 4
  for (int k = ka; k < kb; ++k) {
    f4 u = ld4(&S[k][i0]);
    f4 v0 = ld4(&Pin[k][c0]), v1 = ld4(&Pin[k][c0+4]);
    float uu[4] = {u.x,u.y,u.z,u.w};
    #pragma unroll
    for (int a = 0; a < 4; ++a) { fma4(acc[a][0], uu[a], v0); fma4(acc[a][1], uu[a], v1); }
  }
}

// ---------------------------------------------------------------------------
// k3: per-item chain.  grid (8), block 512.  LDS 143.6 KB.
// ---------------------------------------------------------------------------
__global__ __launch_bounds__(512) void k3_als(float* __restrict__ ws) {
  __shared__ __align__(16) float Ms[96][96];   // M -> M2 -> S3' -> W2
  __shared__ __align__(16) float B1[96][96];   // S1 -> S3 -> TMP^T -> S1'
  __shared__ __align__(16) float B2[96][96];   // scratch -> S2 -> W1 -> S2'
  __shared__ __align__(16) float P[96][32];
  __shared__ __align__(16) float Q[96][32];
  __shared__ __align__(16) float aug[32][64];
  __shared__ __align__(16) float colbuf[2][32];

  int item = blockIdx.x;
  const float* MGp = ws + OFF_MGP + (size_t)item * PBLK;
  float* Tg = ws + OFF_TG + (size_t)item * 9216;
  float* B1f = &B1[0][0];
  float* B2f = &B2[0][0];
  float* Pf  = &P[0][0];
  int t = TID;

  // ---- ph0: unpack M (upper tiles + mirror) and load C1 ----
  for (int e = t; e < 2016; e += 512) {
    if (e < 1248) {
      int tile = e >> 4, q = e & 15;
      int ti, tj; trimap(tile, ti, tj);
      f4 v = ld4(&MGp[tile*64 + q*4]);
      int r = q >> 1, c0 = (q & 1) * 4;
      int i = ti*8 + r, j = tj*8 + c0;
      st4(&Ms[i][j], v);
      Ms[j+0][i] = v.x; Ms[j+1][i] = v.y; Ms[j+2][i] = v.z; Ms[j+3][i] = v.w;
    } else {
      int u = e - 1248;                       // 768 f4 of C1 (96x32)
      int i = u >> 3, c0 = (u & 7) * 4;
      st4(&P[i][c0], ld4(&MGp[COFF + i*48 + c0]));
    }
  }
  __syncthreads();

  // ---- ph1: S1 = M^2 * 2^-27 -> B1  (144 8x8 tiles, ksplit2, scratch B2)
  {
    f4 acc[8][2];
    #pragma unroll
    for (int a = 0; a < 8; ++a) { acc[a][0] = f4zero(); acc[a][1] = f4zero(); }
    int ch = 0, ti = 0, tj = 0;
    if (t < 288) {
      ch = t / 144; int tile = t % 144; ti = tile/12; tj = tile%12;
      #pragma unroll 4
      for (int k = ch*48; k < ch*48+48; ++k) tile8_step(acc, &Ms[k][ti*8], &Ms[k][tj*8]);
      if (ch == 1) {
        int tile = t - 144;
        #pragma unroll
        for (int a = 0; a < 8; ++a) { st4(&B2f[tile*64 + a*8], acc[a][0]); st4(&B2f[tile*64 + a*8 + 4], acc[a][1]); }
      }
    }
    __syncthreads();
    if (t < 144) {
      #pragma unroll
      for (int a = 0; a < 8; ++a) {
        f4 s0 = add4(acc[a][0], ld4(&B2f[t*64 + a*8]));
        f4 s1 = add4(acc[a][1], ld4(&B2f[t*64 + a*8 + 4]));
        st4(&B1[ti*8 + a][tj*8],     scl4(s0, SC27));
        st4(&B1[ti*8 + a][tj*8 + 4], scl4(s1, SC27));
      }
    }
  }
  __syncthreads();

  // ---- ph2: S2 = S1^2 -> B2  ||  Q = S1*C1 ----
  if (t < 144) {
    int ti = t/12, tj = t%12;
    f4 acc[8][2];
    #pragma unroll
    for (int a = 0; a < 8; ++a) { acc[a][0] = f4zero(); acc[a][1] = f4zero(); }
    #pragma unroll 4
    for (int k = 0; k < 96; ++k) tile8_step(acc, &B1[k][ti*8], &B1[k][tj*8]);
    #pragma unroll
    for (int a = 0; a < 8; ++a) { st4(&B2[ti*8+a][tj*8], acc[a][0]); st4(&B2[ti*8+a][tj*8+4], acc[a][1]); }
  } else if (t < 240) {
    int u = t - 144; int i0 = (u >> 2) * 4, c0 = (u & 3) * 8;
    f4 acc[4][2] = {{f4zero(),f4zero()},{f4zero(),f4zero()},{f4zero(),f4zero()},{f4zero(),f4zero()}};
    app_tile(B1, P, acc, i0, c0, 0, 96);
    #pragma unroll
    for (int a = 0; a < 4; ++a) { st4(&Q[i0+a][c0], acc[a][0]); st4(&Q[i0+a][c0+4], acc[a][1]); }
  }
  __syncthreads();

  // ---- ph3: S3 = S2^2 -> B1  ||  P = S2*Q ----
  if (t < 144) {
    int ti = t/12, tj = t%12;
    f4 acc[8][2];
    #pragma unroll
    for (int a = 0; a < 8; ++a) { acc[a][0] = f4zero(); acc[a][1] = f4zero(); }
    #pragma unroll 4
    for (int k = 0; k < 96; ++k) tile8_step(acc, &B2[k][ti*8], &B2[k][tj*8]);
    #pragma unroll
    for (int a = 0; a < 8; ++a) { st4(&B1[ti*8+a][tj*8], acc[a][0]); st4(&B1[ti*8+a][tj*8+4], acc[a][1]); }
  } else if (t < 240) {
    int u = t - 144; int i0 = (u >> 2) * 4, c0 = (u & 3) * 8;
    f4 acc[4][2] = {{f4zero(),f4zero()},{f4zero(),f4zero()},{f4zero(),f4zero()},{f4zero(),f4zero()}};
    app_tile(B2, Q, acc, i0, c0, 0, 96);
    #pragma unroll
    for (int a = 0; a < 4; ++a) { st4(&P[i0+a][c0], acc[a][0]); st4(&P[i0+a][c0+4], acc[a][1]); }
  }
  __syncthreads();

  // ---- ph4: Q = S3*P (ksplit2, scratch B2... use upper region beyond S2? S2 live!)
  // S2 (B2) is dead after ph3.  scratch = B2.
  {
    f4 acc[4][2] = {{f4zero(),f4zero()},{f4zero(),f4zero()},{f4zero(),f4zero()},{f4zero(),f4zero()}};
    int tt = 0;
    if (t < 192) {
      int ch = t / 96; tt = t % 96;
      int i0 = (tt >> 2) * 4, c0 = (tt & 3) * 8;
      app_tile(B1, P, acc, i0, c0, ch*48, ch*48+48);
      if (ch == 1) {
        #pragma unroll
        for (int a = 0; a < 4; ++a) { st4(&B2f[tt*32 + a*8], acc[a][0]); st4(&B2f[tt*32 + a*8 + 4], acc[a][1]); }
      }
    } else if (t < 224) {
      int i = t - 192;
      for (int j = 0; j < 32; j += 4)
        st4(&aug[i][32+j], make_float4(i==j?1.f:0.f, i==j+1?1.f:0.f, i==j+2?1.f:0.f, i==j+3?1.f:0.f));
    }
    __syncthreads();
    if (t < 96) {
      int i0 = (tt >> 2) * 4, c0 = (tt & 3) * 8;
      #pragma unroll
      for (int a = 0; a < 4; ++a) {
        st4(&Q[i0+a][c0],   add4(acc[a][0], ld4(&B2f[tt*32 + a*8])));
        st4(&Q[i0+a][c0+4], add4(acc[a][1], ld4(&B2f[tt*32 + a*8 + 4])));
      }
    }
  }
  __syncthreads();

  // ---- ph5: Gram1 = Q^T Q (32x32, ksplit4, scratch P) -> aug[:,0:32]
  {
    f4 acc[4] = {f4zero(),f4zero(),f4zero(),f4zero()};
    int tt = 0;
    if (t < 256) {
      int ch = t / 64; tt = t % 64;
      int a0 = (tt >> 3) * 4, b0 = (tt & 7) * 4;
      #pragma unroll 4
      for (int k = ch*24; k < ch*24+24; ++k) {
        f4 u = ld4(&Q[k][a0]), v = ld4(&Q[k][b0]);
        float uu[4] = {u.x,u.y,u.z,u.w};
        #pragma unroll
        for (int a = 0; a < 4; ++a) fma4(acc[a], uu[a], v);
      }
      if (ch > 0) {
        #pragma unroll
        for (int a = 0; a < 4; ++a) st4(&Pf[(ch-1)*1024 + tt*16 + a*4], acc[a]);
      }
    }
    __syncthreads();
    if (t < 64) {
      int a0 = (tt >> 3) * 4, b0 = (tt & 7) * 4;
      #pragma unroll
      for (int a = 0; a < 4; ++a) {
        f4 s = acc[a];
        #pragma unroll
        for (int p2 = 0; p2 < 3; ++p2) s = add4(s, ld4(&Pf[p2*1024 + tt*16 + a*4]));
        st4(&aug[a0+a][b0], s);
      }
    }
  }
  gauss_jordan(aug, colbuf, 32, 64);          // K1 in aug[:,32:64]

  // ---- ph5b: transpose K1 into aug[:,0:32] ----
  for (int e = t; e < 1024; e += 512) { int m = e >> 5, c = e & 31; aug[c][m] = aug[m][32+c]; }
  __syncthreads();

  // ---- ph6: AK = Q * K1 -> P  (dot over m, K1^T rows in aug[:,0:32]) ----
  if (t < 96) {
    int i0 = (t >> 2) * 4, c0 = (t & 3) * 8;
    float acc[4][8];
    #pragma unroll
    for (int a = 0; a < 4; ++a)
      #pragma unroll
      for (int b = 0; b < 8; ++b) acc[a][b] = 0.f;
    #pragma unroll
    for (int mq = 0; mq < 32; mq += 4) {
      f4 qv[4], kv[8];
      #pragma unroll
      for (int a = 0; a < 4; ++a) qv[a] = ld4(&Q[i0+a][mq]);
      #pragma unroll
      for (int b = 0; b < 8; ++b) kv[b] = ld4(&aug[c0+b][mq]);
      #pragma unroll
      for (int a = 0; a < 4; ++a)
        #pragma unroll
        for (int b = 0; b < 8; ++b) acc[a][b] = dot4(qv[a], kv[b], acc[a][b]);
    }
    #pragma unroll
    for (int a = 0; a < 4; ++a) {
      st4(&P[i0+a][c0],   make_float4(acc[a][0],acc[a][1],acc[a][2],acc[a][3]));
      st4(&P[i0+a][c0+4], make_float4(acc[a][4],acc[a][5],acc[a][6],acc[a][7]));
    }
  }
  __syncthreads();

  // ---- ph7: W1 = AK * P1^T  (dot 8x8 over r=32) -> B2 and Tg ----
  if (t < 144) {
    int i0 = (t/12)*8, j0 = (t%12)*8;
    float acc[8][8];
    #pragma unroll
    for (int a = 0; a < 8; ++a)
      #pragma unroll
      for (int b = 0; b < 8; ++b) acc[a][b] = 0.f;
    #pragma unroll
    for (int cq = 0; cq < 32; cq += 4) {
      f4 av[8], bv[8];
      #pragma unroll
      for (int a = 0; a < 8; ++a) av[a] = ld4(&P[i0+a][cq]);
      #pragma unroll
      for (int b = 0; b < 8; ++b) bv[b] = ld4(&Q[j0+b][cq]);
      #pragma unroll
      for (int a = 0; a < 8; ++a)
        #pragma unroll
        for (int b = 0; b < 8; ++b) acc[a][b] = dot4(av[a], bv[b], acc[a][b]);
    }
    #pragma unroll
    for (int a = 0; a < 8; ++a) {
      f4 w0 = make_float4(acc[a][0],acc[a][1],acc[a][2],acc[a][3]);
      f4 w1 = make_float4(acc[a][4],acc[a][5],acc[a][6],acc[a][7]);
      st4(&B2[i0+a][j0], w0); st4(&B2[i0+a][j0+4], w1);
      st4(&Tg[(i0+a)*96 + j0], w0); st4(&Tg[(i0+a)*96 + j0 + 4], w1);
    }
  }
  __syncthreads();

  // ---- ph8: TMP^T -> B1  (TMP = M - W1*M)  ||  load C2 -> Q[:,0:16] ----
  if (t < 144) {
    int i0 = (t/12)*8, j0 = (t%12)*8;
    f4 acc[8][2];
    #pragma unroll
    for (int a = 0; a < 8; ++a) { acc[a][0] = f4zero(); acc[a][1] = f4zero(); }
    #pragma unroll 4
    for (int k = 0; k < 96; ++k) tile8_step(acc, &B2[k][i0], &Ms[k][j0]);  // W1 sym
    float D[8][8];
    #pragma unroll
    for (int a = 0; a < 8; ++a) {
      f4 m0 = ld4(&Ms[i0+a][j0]), m1 = ld4(&Ms[i0+a][j0+4]);
      D[a][0]=m0.x-acc[a][0].x; D[a][1]=m0.y-acc[a][0].y; D[a][2]=m0.z-acc[a][0].z; D[a][3]=m0.w-acc[a][0].w;
      D[a][4]=m1.x-acc[a][1].x; D[a][5]=m1.y-acc[a][1].y; D[a][6]=m1.z-acc[a][1].z; D[a][7]=m1.w-acc[a][1].w;
    }
    #pragma unroll
    for (int b = 0; b < 8; ++b) {
      st4(&B1[j0+b][i0],   make_float4(D[0][b],D[1][b],D[2][b],D[3][b]));
      st4(&B1[j0+b][i0+4], make_float4(D[4][b],D[5][b],D[6][b],D[7][b]));
    }
  } else if (t < 336) {
    int e = t - 144;                  // 192 tasks, 2 f4 each: C2 96x16
    int i = e >> 1, c0 = (e & 1) * 8;
    st4(&Q[i][c0],   ld4(&MGp[COFF + i*48 + 32 + c0]));
    st4(&Q[i][c0+4], ld4(&MGp[COFF + i*48 + 32 + c0 + 4]));
  }
  __syncthreads();

  // ---- ph9: M2 = TMP - TMP*W1 -> Ms (sym store)  ||  C2' = C2 - W1*C2 -> P[:,0:16]
  if (t < 144) {
    int i0 = (t/12)*8, j0 = (t%12)*8;
    f4 acc[8][2];
    #pragma unroll
    for (int a = 0; a < 8; ++a) { acc[a][0] = f4zero(); acc[a][1] = f4zero(); }
    #pragma unroll 4
    for (int k = 0; k < 96; ++k) tile8_step(acc, &B1[k][i0], &B2[k][j0]);  // TMP[i][k] W1[k][j]
    #pragma unroll
    for (int b = 0; b < 8; ++b) {
      f4 tc0 = ld4(&B1[j0+b][i0]), tc1 = ld4(&B1[j0+b][i0+4]);   // TMP[i0..][j0+b]
      float col[8];
      #pragma unroll
      for (int a = 0; a < 4; ++a) col[a]   = getc(tc0,a) - getc(acc[a][b>>2],   b&3);
      #pragma unroll
      for (int a = 4; a < 8; ++a) col[a]   = getc(tc1,a-4) - getc(acc[a][b>>2], b&3);
      st4(&Ms[j0+b][i0],   make_float4(col[0],col[1],col[2],col[3]));
      st4(&Ms[j0+b][i0+4], make_float4(col[4],col[5],col[6],col[7]));
    }
  } else if (t < 192) {
    int u = t - 144; int i0 = (u >> 1) * 4, c0 = (u & 1) * 8;
    f4 acc[4][2] = {{f4zero(),f4zero()},{f4zero(),f4zero()},{f4zero(),f4zero()},{f4zero(),f4zero()}};
    app_tile(B2, Q, acc, i0, c0, 0, 96);                          // W1 sym
    #pragma unroll
    for (int a = 0; a < 4; ++a) {
      f4 q0 = ld4(&Q[i0+a][c0]), q1 = ld4(&Q[i0+a][c0+4]);
      st4(&P[i0+a][c0],   sub4(q0, acc[a][0]));
      st4(&P[i0+a][c0+4], sub4(q1, acc[a][1]));
    }
  }
  __syncthreads();

  // ---- ph10: S1' = M2^2 * 2^-27 -> B1 (ksplit2, scratch B2; W1 on-chip dead)
  {
    f4 acc[8][2];
    #pragma unroll
    for (int a = 0; a < 8; ++a) { acc[a][0] = f4zero(); acc[a][1] = f4zero(); }
    int ti = 0, tj = 0;
    if (t < 288) {
      int ch = t / 144; int tile = t % 144; ti = tile/12; tj = tile%12;
      #pragma unroll 4
      for (int k = ch*48; k < ch*48+48; ++k) tile8_step(acc, &Ms[k][ti*8], &Ms[k][tj*8]);
      if (ch == 1) {
        int tile = t - 144;
        #pragma unroll
        for (int a = 0; a < 8; ++a) { st4(&B2f[tile*64 + a*8], acc[a][0]); st4(&B2f[tile*64 + a*8 + 4], acc[a][1]); }
      }
    }
    __syncthreads();
    if (t < 144) {
      #pragma unroll
      for (int a = 0; a < 8; ++a) {
        f4 s0 = add4(acc[a][0], ld4(&B2f[t*64 + a*8]));
        f4 s1 = add4(acc[a][1], ld4(&B2f[t*64 + a*8 + 4]));
        st4(&B1[ti*8 + a][tj*8],     scl4(s0, SC27));
        st4(&B1[ti*8 + a][tj*8 + 4], scl4(s1, SC27));
      }
    }
  }
  __syncthreads();

  // ---- ph11: S2' = S1'^2 -> B2  ||  Q[:,0:16] = S1'*C2' ----
  if (t < 144) {
    int ti = t/12, tj = t%12;
    f4 acc[8][2];
    #pragma unroll
    for (int a = 0; a < 8; ++a) { acc[a][0] = f4zero(); acc[a][1] = f4zero(); }
    #pragma unroll 4
    for (int k = 0; k < 96; ++k) tile8_step(acc, &B1[k][ti*8], &B1[k][tj*8]);
    #pragma unroll
    for (int a = 0; a < 8; ++a) { st4(&B2[ti*8+a][tj*8], acc[a][0]); st4(&B2[ti*8+a][tj*8+4], acc[a][1]); }
  } else if (t < 192) {
    int u = t - 144; int i0 = (u >> 1) * 4, c0 = (u & 1) * 8;
    f4 acc[4][2] = {{f4zero(),f4zero()},{f4zero(),f4zero()},{f4zero(),f4zero()},{f4zero(),f4zero()}};
    app_tile(B1, P, acc, i0, c0, 0, 96);
    #pragma unroll
    for (int a = 0; a < 4; ++a) { st4(&Q[i0+a][c0], acc[a][0]); st4(&Q[i0+a][c0+4], acc[a][1]); }
  }
  __syncthreads();

  // ---- ph12: S3' = S2'^2 -> Ms  ||  P[:,0:16] = S2'*Q ----
  if (t < 144) {
    int ti = t/12, tj = t%12;
    f4 acc[8][2];
    #pragma unroll
    for (int a = 0; a < 8; ++a) { acc[a][0] = f4zero(); acc[a][1] = f4zero(); }
    #pragma unroll 4
    for (int k = 0; k < 96; ++k) tile8_step(acc, &B2[k][ti*8], &B2[k][tj*8]);
    #pragma unroll
    for (int a = 0; a < 8; ++a) { st4(&Ms[ti*8+a][tj*8], acc[a][0]); st4(&Ms[ti*8+a][tj*8+4], acc[a][1]); }
  } else if (t < 192) {
    int u = t - 144; int i0 = (u >> 1) * 4, c0 = (u & 1) * 8;
    f4 acc[4][2] = {{f4zero(),f4zero()},{f4zero(),f4zero()},{f4zero(),f4zero()},{f4zero(),f4zero()}};
    app_tile(B2, Q, acc, i0, c0, 0, 96);
    #pragma unroll
    for (int a = 0; a < 4; ++a) { st4(&P[i0+a][c0], acc[a][0]); st4(&P[i0+a][c0+4], acc[a][1]); }
  }
  __syncthreads();

  // ---- ph13: Q[:,0:16] = S3'*P (ksplit2, scratch B1) + I16 into aug ----
  {
    f4 acc[4][2] = {{f4zero(),f4zero()},{f4zero(),f4zero()},{f4zero(),f4zero()},{f4zero(),f4zero()}};
    int tt = 0;
    if (t < 96) {
      int ch = t / 48; tt = t % 48;
      int i0 = (tt >> 1) * 4, c0 = (tt & 1) * 8;
      app_tile(Ms, P, acc, i0, c0, ch*48, ch*48+48);
      if (ch == 1) {
        #pragma unroll
        for (int a = 0; a < 4; ++a) { st4(&B1f[tt*32 + a*8], acc[a][0]); st4(&B1f[tt*32 + a*8 + 4], acc[a][1]); }
      }
    } else if (t < 112) {
      int i = t - 96;
      for (int j = 0; j < 16; j += 4)
        st4(&aug[i][16+j], make_float4(i==j?1.f:0.f, i==j+1?1.f:0.f, i==j+2?1.f:0.f, i==j+3?1.f:0.f));
    }
    __syncthreads();
    if (t < 48) {
      int i0 = (tt >> 1) * 4, c0 = (tt & 1) * 8;
      #pragma unroll
      for (int a = 0; a < 4; ++a) {
        st4(&Q[i0+a][c0],   add4(acc[a][0], ld4(&B1f[tt*32 + a*8])));
        st4(&Q[i0+a][c0+4], add4(acc[a][1], ld4(&B1f[tt*32 + a*8 + 4])));
      }
    }
  }
  __syncthreads();

  // ---- ph14: Gram2 = Q^T Q (16x16, ksplit8, scratch P) -> aug[:,0:16] ----
  {
    f4 acc[4] = {f4zero(),f4zero(),f4zero(),f4zero()};
    int tt = 0;
    if (t < 128) {
      int ch = t / 16; tt = t % 16;
      int a0 = (tt >> 2) * 4, b0 = (tt & 3) * 4;
      #pragma unroll 4
      for (int k = ch*12; k < ch*12+12; ++k) {
        f4 u = ld4(&Q[k][a0]), v = ld4(&Q[k][b0]);
        float uu[4] = {u.x,u.y,u.z,u.w};
        #pragma unroll
        for (int a = 0; a < 4; ++a) fma4(acc[a], uu[a], v);
      }
      if (ch > 0) {
        #pragma unroll
        for (int a = 0; a < 4; ++a) st4(&Pf[(ch-1)*256 + tt*16 + a*4], acc[a]);
      }
    }
    __syncthreads();
    if (t < 16) {
      int a0 = (tt >> 2) * 4, b0 = (tt & 3) * 4;
      #pragma unroll
      for (int a = 0; a < 4; ++a) {
        f4 s = acc[a];
        #pragma unroll
        for (int p2 = 0; p2 < 7; ++p2) s = add4(s, ld4(&Pf[p2*256 + tt*16 + a*4]));
        st4(&aug[a0+a][b0], s);
      }
    }
  }
  gauss_jordan(aug, colbuf, 16, 32);           // K2 in aug[:,16:32]

  // ---- ph14b: transpose K2 into aug[:,0:16] ----
  if (t < 256) { int m = t >> 4, c = t & 15; aug[c][m] = aug[m][16+c]; }
  __syncthreads();

  // ---- ph15: AK2 = Q * K2 -> P[:,0:16] ----
  if (t < 48) {
    int i0 = (t >> 1) * 4, c0 = (t & 1) * 8;
    float acc[4][8];
    #pragma unroll
    for (int a = 0; a < 4; ++a)
      #pragma unroll
      for (int b = 0; b < 8; ++b) acc[a][b] = 0.f;
    #pragma unroll
    for (int mq = 0; mq < 16; mq += 4) {
      f4 qv[4], kv[8];
      #pragma unroll
      for (int a = 0; a < 4; ++a) qv[a] = ld4(&Q[i0+a][mq]);
      #pragma unroll
      for (int b = 0; b < 8; ++b) kv[b] = ld4(&aug[c0+b][mq]);
      #pragma unroll
      for (int a = 0; a < 4; ++a)
        #pragma unroll
        for (int b = 0; b < 8; ++b) acc[a][b] = dot4(qv[a], kv[b], acc[a][b]);
    }
    #pragma unroll
    for (int a = 0; a < 4; ++a) {
      st4(&P[i0+a][c0],   make_float4(acc[a][0],acc[a][1],acc[a][2],acc[a][3]));
      st4(&P[i0+a][c0+4], make_float4(acc[a][4],acc[a][5],acc[a][6],acc[a][7]));
    }
  }
  __syncthreads();

  // ---- ph16: W2 = AK2 * P2^T (dot 8x8 over r=16) -> Ms ----
  if (t < 144) {
    int i0 = (t/12)*8, j0 = (t%12)*8;
    float acc[8][8];
    #pragma unroll
    for (int a = 0; a < 8; ++a)
      #pragma unroll
      for (int b = 0; b < 8; ++b) acc[a][b] = 0.f;
    #pragma unroll
    for (int cq = 0; cq < 16; cq += 4) {
      f4 av[8], bv[8];
      #pragma unroll
      for (int a = 0; a < 8; ++a) av[a] = ld4(&P[i0+a][cq]);
      #pragma unroll
      for (int b = 0; b < 8; ++b) bv[b] = ld4(&Q[j0+b][cq]);
      #pragma unroll
      for (int a = 0; a < 8; ++a)
        #pragma unroll
        for (int b = 0; b < 8; ++b) acc[a][b] = dot4(av[a], bv[b], acc[a][b]);
    }
    #pragma unroll
    for (int a = 0; a < 8; ++a) {
      st4(&Ms[i0+a][j0],   make_float4(acc[a][0],acc[a][1],acc[a][2],acc[a][3]));
      st4(&Ms[i0+a][j0+4], make_float4(acc[a][4],acc[a][5],acc[a][6],acc[a][7]));
    }
  }
  __syncthreads();

  // ---- ph17: T = W1 + W2 : Tg += W2 ----
  {
    const float* Msf = &Ms[0][0];
    for (int e = TID*4; e < 9216; e += 2048)
      st4(&Tg[e], add4(ld4(&Tg[e]), ld4(&Msf[e])));
  }
}

// ---------------------------------------------------------------------------
// k4: out = T @ X.  grid (72, 8), block 256 (128 cols / WG).
// ---------------------------------------------------------------------------
__global__ __launch_bounds__(256) void k4_out(
    const float* __restrict__ x, const float* __restrict__ ws,
    float* __restrict__ out) {
  __shared__ __align__(16) float Tt[96][100];
  int jb = blockIdx.x, item = blockIdx.y;
  const float* Tg = ws + OFF_TG + (size_t)item * 9216;
  for (int e = TID * 4; e < 9216; e += 1024) {
    f4 v = ld4(&Tg[e]);
    int i = e / 96, k = e % 96;
    Tt[k][i] = v.x; Tt[k+1][i] = v.y; Tt[k+2][i] = v.z; Tt[k+3][i] = v.w;
  }
  __syncthreads();

  int jq = (TID % 32) * 4, ig = TID / 32;
  int i0 = ig * 12;
  int col = jb * 128 + jq;
  const float* X = x + (size_t)item * 96 * 9216;
  f4 acc[12];
  #pragma unroll
  for (int a = 0; a < 12; ++a) acc[a] = f4zero();

  for (int k = 0; k < 96; ++k) {
    f4 xv = ld4(&X[(size_t)k * 9216 + col]);
    f4 t0 = ld4(&Tt[k][i0]), t1 = ld4(&Tt[k][i0+4]), t2 = ld4(&Tt[k][i0+8]);
    fma4(acc[0], t0.x, xv); fma4(acc[1], t0.y, xv); fma4(acc[2], t0.z, xv); fma4(acc[3], t0.w, xv);
    fma4(acc[4], t1.x, xv); fma4(acc[5], t1.y, xv); fma4(acc[6], t1.z, xv); fma4(acc[7], t1.w, xv);
    fma4(acc[8], t2.x, xv); fma4(acc[9], t2.y, xv); fma4(acc[10], t2.z, xv); fma4(acc[11], t2.w, xv);
  }
  float* O = out + (size_t)item * 96 * 9216;
  #pragma unroll
  for (int a = 0; a < 12; ++a) st4(&O[(size_t)(i0 + a) * 9216 + col], acc[a]);
}

// ---------------------------------------------------------------------------
extern "C" void kernel_launch(void* const* d_in, const int* in_sizes, int n_in,
                              void* d_out, int out_size, void* d_ws, size_t ws_size,
                              hipStream_t stream) {
  (void)in_sizes; (void)n_in; (void)out_size; (void)ws_size;
  const float* x   = (const float*)d_in[0];
  const float* b01 = (const float*)d_in[2];  // B0_1 (9216 x 32)
  const float* b02 = (const float*)d_in[4];  // B0_2 (9216 x 16)
  float* out = (float*)d_out;
  float* ws  = (float*)d_ws;

  k1_partials<<<dim3(NCH, 8), 512, 0, stream>>>(x, b01, b02, ws);
  k2_reduce<<<dim3(75), 256, 0, stream>>>(ws);
  k3_als<<<dim3(8), 512, 0, stream>>>(ws);
  k4_out<<<dim3(72, 8), 256, 0, stream>>>(x, ws, out);
}

// Round 5
// 222.911 us; speedup vs baseline: 3.8872x; 1.1077x over previous
//
#include <hip/hip_runtime.h>

// ---------------------------------------------------------------------------
// MRLR feature extractor, round 5: power-iteration + repeated squaring, with
// every heavy k3 phase k-split across 288-480 of 512 lanes.
//   W1 = proj(M^14 C1): S1=M^2*2^-27, S2=S1^2, S3=S2^2, basis = S3*S2*S1*C1
//   M2 = (I-W1)M(I-W1); W2 = proj(M2^14 (C2 - W1 C2)); T = W1 + W2; out = T X
// k1: triangle M = X X^T + C = X[B01|B02], split-K partials, ksplit3 in-WG.
// k2: reduce 32 partials.  k3: per-item chain in LDS (8 WG x 512).  k4: T X.
// ---------------------------------------------------------------------------

#define TID ((int)threadIdx.x)
typedef float4 f4;

#define NCH 32
#define CHK 288            // 9216/32, staged as 6 sub-chunks of 48
#define PBLK 9600          // 78*64 M-tiles + 96*48 C
#define COFF 4992

// workspace layout (float offsets) — total 2,608,128 floats = 10.43 MB
#define OFF_PART 0                 // 8*32*9600
#define OFF_MGP  2457600           // 8*9600
#define OFF_TG   2534400           // 8*9216
#define SC27 (1.0f/134217728.0f)   // 2^-27

__device__ __forceinline__ f4 ld4(const float* p) { return *(const f4*)p; }
__device__ __forceinline__ void st4(float* p, f4 v) { *(f4*)p = v; }
__device__ __forceinline__ f4 f4zero() { return make_float4(0.f,0.f,0.f,0.f); }
__device__ __forceinline__ f4 add4(f4 a, f4 b){ return make_float4(a.x+b.x,a.y+b.y,a.z+b.z,a.w+b.w); }
__device__ __forceinline__ f4 sub4(f4 a, f4 b){ return make_float4(a.x-b.x,a.y-b.y,a.z-b.z,a.w-b.w); }
__device__ __forceinline__ f4 scl4(f4 a, float s){ return make_float4(a.x*s,a.y*s,a.z*s,a.w*s); }
__device__ __forceinline__ void fma4(f4& a, float s, f4 v) {
  a.x = fmaf(s,v.x,a.x); a.y = fmaf(s,v.y,a.y); a.z = fmaf(s,v.z,a.z); a.w = fmaf(s,v.w,a.w);
}
__device__ __forceinline__ float getc(f4 v, int u) {
  return u==0 ? v.x : (u==1 ? v.y : (u==2 ? v.z : v.w));
}
__device__ __forceinline__ float dot4(f4 a, f4 b, float acc) {
  acc = fmaf(a.x,b.x,acc); acc = fmaf(a.y,b.y,acc);
  acc = fmaf(a.z,b.z,acc); acc = fmaf(a.w,b.w,acc); return acc;
}
__device__ __forceinline__ void trimap(int t, int& ti, int& tj) {
  int rem = t; ti = 0;
  #pragma unroll
  for (int r = 0; r < 12; ++r) { int w = 12 - r; if (rem < w) { ti = r; break; } rem -= w; }
  tj = ti + rem;
}
__device__ __forceinline__ void init8(f4 acc[8][2]) {
  #pragma unroll
  for (int a = 0; a < 8; ++a) { acc[a][0] = f4zero(); acc[a][1] = f4zero(); }
}
__device__ __forceinline__ void init4(f4 acc[4][2]) {
  #pragma unroll
  for (int a = 0; a < 4; ++a) { acc[a][0] = f4zero(); acc[a][1] = f4zero(); }
}
__device__ __forceinline__ void tile8_step(f4 acc[8][2], const float* u, const float* v) {
  f4 u0 = ld4(u), u1 = ld4(u+4), v0 = ld4(v), v1 = ld4(v+4);
  float aa[8] = {u0.x,u0.y,u0.z,u0.w,u1.x,u1.y,u1.z,u1.w};
  #pragma unroll
  for (int a = 0; a < 8; ++a) { fma4(acc[a][0], aa[a], v0); fma4(acc[a][1], aa[a], v1); }
}

// ---------------------------------------------------------------------------
// k1: grid (NCH, 8), block 512.  450 active: 3 k-parity x (78 tri-M + 72 C).
// ---------------------------------------------------------------------------
__global__ __launch_bounds__(512) void k1_partials(
    const float* __restrict__ x, const float* __restrict__ b01,
    const float* __restrict__ b02, float* __restrict__ ws) {
  __shared__ __align__(16) float Xst[48][100];
  __shared__ __align__(16) float Bs[48][52];
  __shared__ __align__(16) float red[19200];
  int kc = blockIdx.x, item = blockIdx.y;
  const float* X = x + (size_t)item * 96 * 9216;
  float* base = ws + OFF_PART + (size_t)(item * NCH + kc) * PBLK;

  int t = TID, kh = 0, tt = 0;
  const float* ap = nullptr; const float* bp = nullptr;
  float* op = nullptr; int os = 0; bool isM = false;
  bool active = (t < 450);
  if (active) {
    kh = t / 150; tt = t % 150;
    if (tt < 78) {
      int ti, tj; trimap(tt, ti, tj);
      ap = &Xst[0][ti*8]; bp = &Xst[0][tj*8];
      op = base + tt*64; os = 8; isM = true;
    } else {
      int u = tt - 78; int i0 = (u/6)*8, c0 = (u%6)*8;
      ap = &Xst[0][i0]; bp = &Bs[0][c0];
      op = base + COFF + i0*48 + c0; os = 48;
    }
  }

  f4 acc[8][2]; init8(acc);

  for (int sc = 0; sc < 6; ++sc) {
    int k0 = kc * CHK + sc * 48;
    __syncthreads();
    for (int e = TID; e < 1152; e += 512) {          // X slab transposed
      int i = e / 12, kq = (e % 12) * 4;
      f4 v = ld4(&X[(size_t)i * 9216 + k0 + kq]);
      Xst[kq][i] = v.x; Xst[kq+1][i] = v.y; Xst[kq+2][i] = v.z; Xst[kq+3][i] = v.w;
    }
    for (int e = TID; e < 384; e += 512) {           // B01
      int kk = e / 8, cq = (e % 8) * 4;
      st4(&Bs[kk][cq], ld4(&b01[(size_t)(k0 + kk) * 32 + cq]));
    }
    for (int e = TID; e < 192; e += 512) {           // B02
      int kk = e / 4, cq = (e % 4) * 4;
      st4(&Bs[kk][32+cq], ld4(&b02[(size_t)(k0 + kk) * 16 + cq]));
    }
    __syncthreads();
    if (active) {
      int asr = 100, bsr = isM ? 100 : 52;
      const float* ar = ap + kh * asr;
      const float* br = bp + kh * bsr;
      #pragma unroll 4
      for (int kk = kh; kk < 48; kk += 3) {
        tile8_step(acc, ar, br);
        ar += 3 * asr; br += 3 * bsr;
      }
    }
  }
  __syncthreads();
  if (active && kh) {
    float* r = &red[(kh-1)*9600 + tt*64];
    #pragma unroll
    for (int a = 0; a < 8; ++a) { st4(&r[a*8], acc[a][0]); st4(&r[a*8+4], acc[a][1]); }
  }
  __syncthreads();
  if (active && kh == 0) {
    #pragma unroll
    for (int a = 0; a < 8; ++a) {
      f4 s0 = add4(acc[a][0], add4(ld4(&red[tt*64 + a*8]),     ld4(&red[9600 + tt*64 + a*8])));
      f4 s1 = add4(acc[a][1], add4(ld4(&red[tt*64 + a*8 + 4]), ld4(&red[9600 + tt*64 + a*8 + 4])));
      st4(op + a*os, s0); st4(op + a*os + 4, s1);
    }
  }
}

// ---------------------------------------------------------------------------
// k2: reduce NCH partials.  grid 75 x 256.
// ---------------------------------------------------------------------------
__global__ __launch_bounds__(256) void k2_reduce(float* __restrict__ ws) {
  int gid = blockIdx.x * 256 + TID;
  int b = gid / 2400, off = (gid % 2400) * 4;
  const float* p = ws + OFF_PART + (size_t)b * NCH * PBLK + off;
  f4 s = f4zero();
  #pragma unroll 8
  for (int c = 0; c < NCH; ++c) s = add4(s, ld4(p + (size_t)c * PBLK));
  st4(&ws[OFF_MGP + (size_t)b * PBLK + off], s);
}

// ---------------------------------------------------------------------------
// k3 building blocks
// ---------------------------------------------------------------------------
__device__ void gauss_jordan(float (*aug)[64], float (*colbuf)[32], int r, int C) {
  int noct = C >> 3;
  int nthr = r * noct;
  __syncthreads();
  if (TID < r) colbuf[0][TID] = aug[TID][0];
  for (int c = 0; c < r; ++c) {
    __syncthreads();
    if (TID < nthr) {
      int i = TID / noct, j0 = (TID % noct) * 8;
      const float* cb = colbuf[c & 1];
      float f = cb[i] / cb[c];
      int nc = c + 1;
      bool own = (nc < r) && (nc >= j0) && (nc < j0 + 8);
      if (i != c) {
        f4 p0 = ld4(&aug[c][j0]), p1 = ld4(&aug[c][j0+4]);
        f4 v0 = ld4(&aug[i][j0]), v1 = ld4(&aug[i][j0+4]);
        float pr[8] = {p0.x,p0.y,p0.z,p0.w,p1.x,p1.y,p1.z,p1.w};
        float vv[8] = {v0.x,v0.y,v0.z,v0.w,v1.x,v1.y,v1.z,v1.w};
        #pragma unroll
        for (int u = 0; u < 8; ++u)
          vv[u] = (j0 + u == c) ? 0.f : fmaf(-f, pr[u], vv[u]);
        st4(&aug[i][j0], make_float4(vv[0],vv[1],vv[2],vv[3]));
        st4(&aug[i][j0+4], make_float4(vv[4],vv[5],vv[6],vv[7]));
        if (own) colbuf[nc & 1][i] = vv[nc - j0];
      } else {
        if (own) colbuf[nc & 1][i] = aug[c][nc];
      }
    }
  }
  __syncthreads();
  int w = C - r, nq = r * (w >> 2);
  if (TID < nq) {
    int i = TID / (w >> 2), jq = (TID % (w >> 2)) * 4;
    float d = aug[i][i];
    f4 z = ld4(&aug[i][r + jq]);
    z.x /= d; z.y /= d; z.z /= d; z.w /= d;
    st4(&aug[i][r + jq], z);
  }
  __syncthreads();
}

__device__ __forceinline__ void sq_part96(const float (*L)[96], const float (*R)[96],
    f4 acc[8][2], int ti, int tj, int ka, int kb) {
  #pragma unroll 4
  for (int k = ka; k < kb; ++k) tile8_step(acc, &L[k][ti*8], &R[k][tj*8]);
}
__device__ __forceinline__ void st_tile96(float (*D)[96], int ti, int tj, const f4 acc[8][2], float s) {
  #pragma unroll
  for (int a = 0; a < 8; ++a) {
    st4(&D[ti*8+a][tj*8],   scl4(acc[a][0], s));
    st4(&D[ti*8+a][tj*8+4], scl4(acc[a][1], s));
  }
}
__device__ __forceinline__ void ld_add_tile96(const float (*D)[96], int ti, int tj, f4 acc[8][2]) {
  #pragma unroll
  for (int a = 0; a < 8; ++a) {
    acc[a][0] = add4(acc[a][0], ld4(&D[ti*8+a][tj*8]));
    acc[a][1] = add4(acc[a][1], ld4(&D[ti*8+a][tj*8+4]));
  }
}
__device__ __forceinline__ void st_tileT(float (*D)[96], int i0, int j0, const f4 acc[8][2]) {
  #pragma unroll
  for (int b = 0; b < 8; ++b) {
    int h = b>>2, q = b&3;
    st4(&D[j0+b][i0],   make_float4(getc(acc[0][h],q),getc(acc[1][h],q),getc(acc[2][h],q),getc(acc[3][h],q)));
    st4(&D[j0+b][i0+4], make_float4(getc(acc[4][h],q),getc(acc[5][h],q),getc(acc[6][h],q),getc(acc[7][h],q)));
  }
}
__device__ __forceinline__ void thin_part(const float (*S)[96], const float* Pin,
    f4 acc[4][2], int i0, int c0, int ka, int kb) {
  #pragma unroll 4
  for (int k = ka; k < kb; ++k) {
    f4 u = ld4(&S[k][i0]);
    f4 v0 = ld4(&Pin[k*32+c0]), v1 = ld4(&Pin[k*32+c0+4]);
    fma4(acc[0][0],u.x,v0); fma4(acc[0][1],u.x,v1);
    fma4(acc[1][0],u.y,v0); fma4(acc[1][1],u.y,v1);
    fma4(acc[2][0],u.z,v0); fma4(acc[2][1],u.z,v1);
    fma4(acc[3][0],u.w,v0); fma4(acc[3][1],u.w,v1);
  }
}
__device__ __forceinline__ void st_thin(float* D, int i0, int c0, const f4 acc[4][2]) {
  #pragma unroll
  for (int a = 0; a < 4; ++a) {
    st4(&D[(i0+a)*32+c0],   acc[a][0]);
    st4(&D[(i0+a)*32+c0+4], acc[a][1]);
  }
}
__device__ __forceinline__ void ld_add_thin(const float* D, int i0, int c0, f4 acc[4][2]) {
  #pragma unroll
  for (int a = 0; a < 4; ++a) {
    acc[a][0] = add4(acc[a][0], ld4(&D[(i0+a)*32+c0]));
    acc[a][1] = add4(acc[a][1], ld4(&D[(i0+a)*32+c0+4]));
  }
}

// lone square with ksplit3: D = (S^T S)*scale; scratch SCR; 432 active.
__device__ void phase_square_ks3(const float (*S)[96], float (*D)[96], float (*SCR)[96],
                                 float scale, int t) {
  f4 acc[8][2]; init8(acc);
  int ti = 0, tj = 0;
  if (t < 432) {
    int ch = t/144, tile = t%144; ti = tile/12; tj = tile%12;
    sq_part96(S, S, acc, ti, tj, ch*32, ch*32+32);
    if (ch == 1) st_tile96(D, ti, tj, acc, 1.f);
    else if (ch == 2) st_tile96(SCR, ti, tj, acc, 1.f);
  }
  __syncthreads();
  if (t < 144) {
    ld_add_tile96(D, ti, tj, acc);
    ld_add_tile96(SCR, ti, tj, acc);
    st_tile96(D, ti, tj, acc, scale);
  }
  __syncthreads();
}

// square ksplit2 (288) + thin ksplit2 (2*24*ncg): D = S^T S; Tout = S*Tin.
__device__ void phase_sq_thin(const float (*S)[96], float (*D)[96],
                              const float* Tin, float* Tout, int ncg, int t) {
  f4 acc[8][2]; init8(acc);
  f4 tacc[4][2]; init4(tacc);
  int ti=0, tj=0, i0=0, c0=0;
  int ntt = 24*ncg;
  if (t < 288) {
    int ch = t/144, tile = t%144; ti = tile/12; tj = tile%12;
    sq_part96(S, S, acc, ti, tj, ch*48, ch*48+48);
    if (ch == 1) st_tile96(D, ti, tj, acc, 1.f);
  } else if (t < 288 + 2*ntt) {
    int u = t-288, ch = u/ntt, tt = u%ntt;
    i0 = (tt/ncg)*4; c0 = (tt%ncg)*8;
    thin_part(S, Tin, tacc, i0, c0, ch*48, ch*48+48);
    if (ch == 1) st_thin(Tout, i0, c0, tacc);
  }
  __syncthreads();
  if (t < 144) { ld_add_tile96(D, ti, tj, acc); st_tile96(D, ti, tj, acc, 1.f); }
  else if (t >= 288 && t < 288+ntt) { ld_add_thin(Tout, i0, c0, tacc); st_thin(Tout, i0, c0, tacc); }
  __syncthreads();
}

// thin-only ksplit4 + aug identity init.  scr provides 2 extra 3072 regions.
__device__ void phase_thin_ks4(const float (*S)[96], const float* Tin, float* Tout,
                               float* scr, int ncg, int raug, float (*aug)[64], int t) {
  f4 tacc[4][2]; init4(tacc);
  int i0=0, c0=0;
  int ntt = 24*ncg;
  if (t < 4*ntt) {
    int ch = t/ntt, tt = t%ntt;
    i0 = (tt/ncg)*4; c0 = (tt%ncg)*8;
    thin_part(S, Tin, tacc, i0, c0, ch*24, ch*24+24);
    if (ch == 1) st_thin(Tout, i0, c0, tacc);
    else if (ch == 2) st_thin(scr, i0, c0, tacc);
    else if (ch == 3) st_thin(scr+3072, i0, c0, tacc);
  } else if (t < 4*ntt + raug) {
    int i = t - 4*ntt;
    for (int j = 0; j < raug; j += 4)
      st4(&aug[i][raug+j], make_float4(i==j?1.f:0.f, i==j+1?1.f:0.f,
                                       i==j+2?1.f:0.f, i==j+3?1.f:0.f));
  }
  __syncthreads();
  if (t < ntt) {
    ld_add_thin(Tout, i0, c0, tacc);
    ld_add_thin(scr, i0, c0, tacc);
    ld_add_thin(scr+3072, i0, c0, tacc);
    st_thin(Tout, i0, c0, tacc);
  }
  __syncthreads();
}

// AK = Qb * K (dot-form, K^T rows in aug[:,0:mtot]), msplit2, partial->Pout.
__device__ void phase_ak(const float (*Qb)[32], const float (*augp)[64], float* Pout,
                         int ncg, int mtot, int t) {
  int ntt = 24*ncg;
  float acc[4][8];
  #pragma unroll
  for (int a = 0; a < 4; ++a)
    #pragma unroll
    for (int b = 0; b < 8; ++b) acc[a][b] = 0.f;
  int i0=0, c0=0;
  if (t < 2*ntt) {
    int ch = t/ntt, tt = t%ntt;
    i0 = (tt/ncg)*4; c0 = (tt%ncg)*8;
    int mh = mtot >> 1;
    for (int mq = ch*mh; mq < ch*mh + mh; mq += 4) {
      f4 qv[4], kv[8];
      #pragma unroll
      for (int a = 0; a < 4; ++a) qv[a] = ld4(&Qb[i0+a][mq]);
      #pragma unroll
      for (int b = 0; b < 8; ++b) kv[b] = ld4(&augp[c0+b][mq]);
      #pragma unroll
      for (int a = 0; a < 4; ++a)
        #pragma unroll
        for (int b = 0; b < 8; ++b) acc[a][b] = dot4(qv[a], kv[b], acc[a][b]);
    }
    if (ch == 1) {
      #pragma unroll
      for (int a = 0; a < 4; ++a) {
        st4(&Pout[(i0+a)*32+c0],   make_float4(acc[a][0],acc[a][1],acc[a][2],acc[a][3]));
        st4(&Pout[(i0+a)*32+c0+4], make_float4(acc[a][4],acc[a][5],acc[a][6],acc[a][7]));
      }
    }
  }
  __syncthreads();
  if (t < ntt) {
    #pragma unroll
    for (int a = 0; a < 4; ++a) {
      f4 p0 = ld4(&Pout[(i0+a)*32+c0]), p1 = ld4(&Pout[(i0+a)*32+c0+4]);
      st4(&Pout[(i0+a)*32+c0],
          make_float4(acc[a][0]+p0.x, acc[a][1]+p0.y, acc[a][2]+p0.z, acc[a][3]+p0.w));
      st4(&Pout[(i0+a)*32+c0+4],
          make_float4(acc[a][4]+p1.x, acc[a][5]+p1.y, acc[a][6]+p1.z, acc[a][7]+p1.w));
    }
  }
  __syncthreads();
}

// W = A * Bb^T (dot 8x8 over rtot), ksplit2, dest D (+optional Tg copy).
__device__ void phase_W(const float (*A)[32], const float (*Bb)[32], float (*D)[96],
                        float* Tgp, int rtot, int t) {
  float acc[8][8];
  #pragma unroll
  for (int a = 0; a < 8; ++a)
    #pragma unroll
    for (int b = 0; b < 8; ++b) acc[a][b] = 0.f;
  int i0=0, j0=0;
  if (t < 288) {
    int ch = t/144, tile = t%144; i0 = (tile/12)*8; j0 = (tile%12)*8;
    int rh = rtot >> 1;
    for (int cq = ch*rh; cq < ch*rh + rh; cq += 4) {
      f4 av[8], bv[8];
      #pragma unroll
      for (int a = 0; a < 8; ++a) av[a] = ld4(&A[i0+a][cq]);
      #pragma unroll
      for (int b = 0; b < 8; ++b) bv[b] = ld4(&Bb[j0+b][cq]);
      #pragma unroll
      for (int a = 0; a < 8; ++a)
        #pragma unroll
        for (int b = 0; b < 8; ++b) acc[a][b] = dot4(av[a], bv[b], acc[a][b]);
    }
    if (ch == 1) {
      #pragma unroll
      for (int a = 0; a < 8; ++a) {
        st4(&D[i0+a][j0],   make_float4(acc[a][0],acc[a][1],acc[a][2],acc[a][3]));
        st4(&D[i0+a][j0+4], make_float4(acc[a][4],acc[a][5],acc[a][6],acc[a][7]));
      }
    }
  }
  __syncthreads();
  if (t < 144) {
    #pragma unroll
    for (int a = 0; a < 8; ++a) {
      f4 p0 = ld4(&D[i0+a][j0]), p1 = ld4(&D[i0+a][j0+4]);
      f4 w0 = make_float4(acc[a][0]+p0.x, acc[a][1]+p0.y, acc[a][2]+p0.z, acc[a][3]+p0.w);
      f4 w1 = make_float4(acc[a][4]+p1.x, acc[a][5]+p1.y, acc[a][6]+p1.z, acc[a][7]+p1.w);
      st4(&D[i0+a][j0], w0); st4(&D[i0+a][j0+4], w1);
      if (Tgp) { st4(&Tgp[(i0+a)*96+j0], w0); st4(&Tgp[(i0+a)*96+j0+4], w1); }
    }
  }
  __syncthreads();
}

// ---------------------------------------------------------------------------
// k3: per-item chain.  grid (8), block 512.  LDS 143.9 KB.
// ---------------------------------------------------------------------------
__global__ __launch_bounds__(512) void k3_als(float* __restrict__ ws) {
  __shared__ __align__(16) float Ms[96][96];   // M -> M2 -> S3' -> W2
  __shared__ __align__(16) float B1[96][96];   // S1 -> S3 -> TMP^T -> S1'
  __shared__ __align__(16) float B2[96][96];   // scratch/S2 -> W1 -> S2'
  __shared__ __align__(16) float P[96][32];
  __shared__ __align__(16) float Q[96][32];
  __shared__ __align__(16) float aug[32][64];
  __shared__ __align__(16) float colbuf[2][32];

  int item = blockIdx.x;
  const float* MGp = ws + OFF_MGP + (size_t)item * PBLK;
  float* Tg = ws + OFF_TG + (size_t)item * 9216;
  float* B1f = &B1[0][0];
  float* B2f = &B2[0][0];
  float* Pf  = &P[0][0];
  float* Qf  = &Q[0][0];
  int t = TID;

  // ph0: unpack M (tri + mirror) and load C1 -> P
  for (int e = t; e < 2016; e += 512) {
    if (e < 1248) {
      int tile = e >> 4, q = e & 15;
      int ti, tj; trimap(tile, ti, tj);
      f4 v = ld4(&MGp[tile*64 + q*4]);
      int r = q >> 1, c0 = (q & 1) * 4;
      int i = ti*8 + r, j = tj*8 + c0;
      st4(&Ms[i][j], v);
      Ms[j+0][i] = v.x; Ms[j+1][i] = v.y; Ms[j+2][i] = v.z; Ms[j+3][i] = v.w;
    } else {
      int u = e - 1248;
      int i = u >> 3, c0 = (u & 7) * 4;
      st4(&P[i][c0], ld4(&MGp[COFF + i*48 + c0]));
    }
  }
  __syncthreads();

  phase_square_ks3(Ms, B1, B2, SC27, t);            // ph1: S1 = M^2*s -> B1
  phase_sq_thin(B1, B2, Pf, Qf, 4, t);              // ph2: S2 -> B2 | Q = S1*C1
  phase_sq_thin(B2, B1, Qf, Pf, 4, t);              // ph3: S3 -> B1 | P = S2*Q
  phase_thin_ks4(B1, Pf, Qf, B2f, 4, 32, aug, t);   // ph4: Q = S3*P ; aug I32

  // ph5: Gram1 = Q^T Q -> aug[:,0:32]  (ksplit4, scratch B2f)
  {
    f4 acc[4] = {f4zero(),f4zero(),f4zero(),f4zero()};
    int a0=0, b0=0;
    if (t < 256) {
      int ch = t/64, tt = t%64; a0 = (tt>>3)*4; b0 = (tt&7)*4;
      #pragma unroll 4
      for (int k = ch*24; k < ch*24+24; ++k) {
        f4 u = ld4(&Q[k][a0]), v = ld4(&Q[k][b0]);
        fma4(acc[0],u.x,v); fma4(acc[1],u.y,v); fma4(acc[2],u.z,v); fma4(acc[3],u.w,v);
      }
      if (ch == 1) { for (int a = 0; a < 4; ++a) st4(&aug[a0+a][b0], acc[a]); }
      else if (ch == 2) { for (int a = 0; a < 4; ++a) st4(&B2f[(a0+a)*32+b0], acc[a]); }
      else if (ch == 3) { for (int a = 0; a < 4; ++a) st4(&B2f[1024+(a0+a)*32+b0], acc[a]); }
    }
    __syncthreads();
    if (t < 64) {
      #pragma unroll
      for (int a = 0; a < 4; ++a) {
        f4 s = add4(add4(acc[a], ld4(&aug[a0+a][b0])),
                    add4(ld4(&B2f[(a0+a)*32+b0]), ld4(&B2f[1024+(a0+a)*32+b0])));
        st4(&aug[a0+a][b0], s);
      }
    }
  }
  gauss_jordan(aug, colbuf, 32, 64);                // K1 in aug[:,32:64]

  // ph5b: K1^T -> aug[:,0:32]
  for (int e = t; e < 1024; e += 512) { int m = e >> 5, c = e & 31; aug[c][m] = aug[m][32+c]; }
  __syncthreads();

  phase_ak(Q, aug, Pf, 4, 32, t);                   // ph6: AK = Q*K1 -> P
  phase_W(P, Q, B2, Tg, 32, t);                     // ph7: W1 = AK*Q^T -> B2, Tg

  // ph8: B1 = TMP^T (TMP = M - W1*M) ; co-load C2 -> Q
  {
    f4 acc[8][2]; init8(acc);
    int i0=0, j0=0;
    if (t < 288) {
      int ch = t/144, tile = t%144; int ti = tile/12, tj = tile%12; i0 = ti*8; j0 = tj*8;
      sq_part96(B2, Ms, acc, ti, tj, ch*48, ch*48+48);     // (W1*M)[i][j]
      if (ch == 1) st_tileT(B1, i0, j0, acc);
    } else if (t < 480) {
      int u = t - 288, i = u>>1, c0 = (u&1)*8;
      st4(&Q[i][c0],   ld4(&MGp[COFF + i*48 + 32 + c0]));
      st4(&Q[i][c0+4], ld4(&MGp[COFF + i*48 + 32 + c0 + 4]));
    }
    __syncthreads();
    if (t < 144) {
      #pragma unroll
      for (int b = 0; b < 8; ++b) {
        int h = b>>2, q = b&3;
        f4 olo = make_float4(getc(acc[0][h],q),getc(acc[1][h],q),getc(acc[2][h],q),getc(acc[3][h],q));
        f4 ohi = make_float4(getc(acc[4][h],q),getc(acc[5][h],q),getc(acc[6][h],q),getc(acc[7][h],q));
        f4 plo = ld4(&B1[j0+b][i0]), phi = ld4(&B1[j0+b][i0+4]);
        f4 mlo = ld4(&Ms[j0+b][i0]), mhi = ld4(&Ms[j0+b][i0+4]);    // M symmetric
        st4(&B1[j0+b][i0],   sub4(mlo, add4(olo, plo)));
        st4(&B1[j0+b][i0+4], sub4(mhi, add4(ohi, phi)));
      }
    }
  }
  __syncthreads();

  // ph9: Ms = M2 = TMP - TMP*W1 ; co: P[:,0:16] = C2' = C2 - W1*C2
  {
    f4 acc[8][2]; init8(acc);
    f4 tacc[4][2]; init4(tacc);
    int i0=0, j0=0, ti0=0, tc0=0;
    if (t < 288) {
      int ch = t/144, tile = t%144; int ti = tile/12, tj = tile%12; i0 = ti*8; j0 = tj*8;
      sq_part96(B1, B2, acc, ti, tj, ch*48, ch*48+48);     // (TMP*W1)[i][j]
      if (ch == 1) st_tileT(Ms, i0, j0, acc);
    } else if (t < 384) {
      int u = t-288, ch = u/48, tt = u%48; ti0 = (tt>>1)*4; tc0 = (tt&1)*8;
      thin_part(B2, Qf, tacc, ti0, tc0, ch*48, ch*48+48);  // W1*C2
      if (ch == 1) st_thin(Pf, ti0, tc0, tacc);
    }
    __syncthreads();
    if (t < 144) {
      #pragma unroll
      for (int b = 0; b < 8; ++b) {
        int h = b>>2, q = b&3;
        f4 olo = make_float4(getc(acc[0][h],q),getc(acc[1][h],q),getc(acc[2][h],q),getc(acc[3][h],q));
        f4 ohi = make_float4(getc(acc[4][h],q),getc(acc[5][h],q),getc(acc[6][h],q),getc(acc[7][h],q));
        f4 plo = ld4(&Ms[j0+b][i0]), phi = ld4(&Ms[j0+b][i0+4]);
        f4 tlo = ld4(&B1[j0+b][i0]), thi = ld4(&B1[j0+b][i0+4]);    // TMP[i][j] = B1[j][i]
        st4(&Ms[j0+b][i0],   sub4(tlo, add4(olo, plo)));
        st4(&Ms[j0+b][i0+4], sub4(thi, add4(ohi, phi)));
      }
    } else if (t >= 288 && t < 336) {
      ld_add_thin(Pf, ti0, tc0, tacc);
      #pragma unroll
      for (int a = 0; a < 4; ++a) {
        st4(&Pf[(ti0+a)*32+tc0],   sub4(ld4(&Q[ti0+a][tc0]),   tacc[a][0]));
        st4(&Pf[(ti0+a)*32+tc0+4], sub4(ld4(&Q[ti0+a][tc0+4]), tacc[a][1]));
      }
    }
  }
  __syncthreads();

  phase_square_ks3(Ms, B1, B2, SC27, t);            // ph10: S1' = M2^2*s -> B1
  phase_sq_thin(B1, B2, Pf, Qf, 2, t);              // ph11: S2' -> B2 | Q = S1'*C2'
  phase_sq_thin(B2, Ms, Qf, Pf, 2, t);              // ph12: S3' -> Ms | P = S2'*Q
  phase_thin_ks4(Ms, Pf, Qf, B1f, 2, 16, aug, t);   // ph13: Q = S3'*P ; aug I16

  // ph14: Gram2 = Q^T Q (16x16, ksplit8, scratch B1f) -> aug[:,0:16]
  {
    f4 acc[4] = {f4zero(),f4zero(),f4zero(),f4zero()};
    int a0=0, b0=0, tt=0;
    if (t < 128) {
      int ch = t/16; tt = t%16; a0 = (tt>>2)*4; b0 = (tt&3)*4;
      #pragma unroll 4
      for (int k = ch*12; k < ch*12+12; ++k) {
        f4 u = ld4(&Q[k][a0]), v = ld4(&Q[k][b0]);
        fma4(acc[0],u.x,v); fma4(acc[1],u.y,v); fma4(acc[2],u.z,v); fma4(acc[3],u.w,v);
      }
      if (ch > 0) {
        #pragma unroll
        for (int a = 0; a < 4; ++a) st4(&B1f[(ch-1)*256 + tt*16 + a*4], acc[a]);
      }
    }
    __syncthreads();
    if (t < 16) {
      #pragma unroll
      for (int a = 0; a < 4; ++a) {
        f4 s = acc[a];
        #pragma unroll
        for (int p2 = 0; p2 < 7; ++p2) s = add4(s, ld4(&B1f[p2*256 + tt*16 + a*4]));
        st4(&aug[a0+a][b0], s);
      }
    }
  }
  gauss_jordan(aug, colbuf, 16, 32);                // K2 in aug[:,16:32]

  // ph14b: K2^T -> aug[:,0:16]
  if (t < 256) { int m = t >> 4, c = t & 15; aug[c][m] = aug[m][16+c]; }
  __syncthreads();

  phase_ak(Q, aug, Pf, 2, 16, t);                   // ph15: AK2 = Q*K2 -> P
  phase_W(P, Q, Ms, nullptr, 16, t);                // ph16: W2 = AK2*Q^T -> Ms

  // ph17: Tg += W2
  {
    const float* Msf = &Ms[0][0];
    for (int e = t*4; e < 9216; e += 2048)
      st4(&Tg[e], add4(ld4(&Tg[e]), ld4(&Msf[e])));
  }
}

// ---------------------------------------------------------------------------
// k4: out = T @ X.  grid (72, 8), block 256.
// ---------------------------------------------------------------------------
__global__ __launch_bounds__(256) void k4_out(
    const float* __restrict__ x, const float* __restrict__ ws,
    float* __restrict__ out) {
  __shared__ __align__(16) float Tt[96][100];
  int jb = blockIdx.x, item = blockIdx.y;
  const float* Tg = ws + OFF_TG + (size_t)item * 9216;
  for (int e = TID * 4; e < 9216; e += 1024) {
    f4 v = ld4(&Tg[e]);
    int i = e / 96, k = e % 96;
    Tt[k][i] = v.x; Tt[k+1][i] = v.y; Tt[k+2][i] = v.z; Tt[k+3][i] = v.w;
  }
  __syncthreads();

  int jq = (TID % 32) * 4, ig = TID / 32;
  int i0 = ig * 12;
  int col = jb * 128 + jq;
  const float* X = x + (size_t)item * 96 * 9216;
  f4 acc[12];
  #pragma unroll
  for (int a = 0; a < 12; ++a) acc[a] = f4zero();

  for (int k = 0; k < 96; ++k) {
    f4 xv = ld4(&X[(size_t)k * 9216 + col]);
    f4 t0 = ld4(&Tt[k][i0]), t1 = ld4(&Tt[k][i0+4]), t2 = ld4(&Tt[k][i0+8]);
    fma4(acc[0], t0.x, xv); fma4(acc[1], t0.y, xv); fma4(acc[2], t0.z, xv); fma4(acc[3], t0.w, xv);
    fma4(acc[4], t1.x, xv); fma4(acc[5], t1.y, xv); fma4(acc[6], t1.z, xv); fma4(acc[7], t1.w, xv);
    fma4(acc[8], t2.x, xv); fma4(acc[9], t2.y, xv); fma4(acc[10], t2.z, xv); fma4(acc[11], t2.w, xv);
  }
  float* O = out + (size_t)item * 96 * 9216;
  #pragma unroll
  for (int a = 0; a < 12; ++a) st4(&O[(size_t)(i0 + a) * 9216 + col], acc[a]);
}

// ---------------------------------------------------------------------------
extern "C" void kernel_launch(void* const* d_in, const int* in_sizes, int n_in,
                              void* d_out, int out_size, void* d_ws, size_t ws_size,
                              hipStream_t stream) {
  (void)in_sizes; (void)n_in; (void)out_size; (void)ws_size;
  const float* x   = (const float*)d_in[0];
  const float* b01 = (const float*)d_in[2];
  const float* b02 = (const float*)d_in[4];
  float* out = (float*)d_out;
  float* ws  = (float*)d_ws;

  k1_partials<<<dim3(NCH, 8), 512, 0, stream>>>(x, b01, b02, ws);
  k2_reduce<<<dim3(75), 256, 0, stream>>>(ws);
  k3_als<<<dim3(8), 512, 0, stream>>>(ws);
  k4_out<<<dim3(72, 8), 256, 0, stream>>>(x, ws, out);
}